// Round 2
// baseline (478.519 us; speedup 1.0000x reference)
//
#include <hip/hip_runtime.h>

#define N_NODES 32000
#define NPG     1000
#define BSZ     32
#define NEDGE   512000
#define H       128
#define NL      3
#define NR      8
#define NKK     1152    // K dim: 8*128 rel chunks + 128 self chunk
#define ASTR    1160    // A_sh row stride in shorts (pad 8 -> bank-conflict-free)
#define NBIN2   262144  // 32768 dst bins x 8 rel sub-bins (pow2-padded; bins >= 256000 empty)

typedef __attribute__((ext_vector_type(8))) short short8;
typedef __attribute__((ext_vector_type(4))) float float4v;

__device__ __forceinline__ float bf2f(unsigned short u) {
  union { unsigned int i; float f; } v;
  v.i = ((unsigned int)u) << 16;
  return v.f;
}
__device__ __forceinline__ unsigned short f2bf(float f) {
  union { float f; unsigned int i; } v;
  v.f = f;
  unsigned int x = v.i;
  return (unsigned short)((x + 0x7FFFu + ((x >> 16) & 1u)) >> 16);  // RNE
}

// ---------------- fused prep: cvtX | cvtB | per-(dst,rel) count | graph hist ----------
__global__ __launch_bounds__(256) void k_prep(
    const float* __restrict__ x, const float* __restrict__ W_rel,
    const float* __restrict__ W_self, const int* __restrict__ dst,
    const int* __restrict__ etype, const int* __restrict__ graph_id,
    unsigned short* __restrict__ hb, unsigned short* __restrict__ Bt,
    int* __restrict__ cnt, int* __restrict__ gcount)
{
  const int b = blockIdx.x, t = threadIdx.x;
  if (b < 4000) {                       // x fp32 -> h0 bf16
    const size_t i = ((size_t)b * 256 + t) * 4;
    float4 v = *(const float4*)(x + i);
    ushort4 u = { f2bf(v.x), f2bf(v.y), f2bf(v.z), f2bf(v.w) };
    *(ushort4*)(hb + i) = u;
  } else if (b < 5728) {                // weights -> Bt2[l][o=0..127][kk=0..1151]
    const int g = (b - 4000) * 256 + t;  // 0..442367 enumerates (l, o, kk)
    const int l = g / (H * NKK);
    const int rem = g - l * (H * NKK);
    const int o = rem / NKK;
    const int kk = rem - o * NKK;
    float v = (kk < 1024)
        ? W_rel[(((size_t)l * NR + (kk >> 7)) * H + (kk & 127)) * H + o]
        : W_self[((size_t)l * H + (kk - 1024)) * H + o];
    Bt[g] = f2bf(v);
  } else if (b < 7728) {                // per-(dst,rel) edge counts
    const int e = (b - 5728) * 256 + t;
    atomicAdd(&cnt[dst[e] * 8 + etype[e]], 1);
  } else {                              // graph histogram (125 blocks)
    __shared__ int hist[BSZ];
    if (t < BSZ) hist[t] = 0;
    __syncthreads();
    const int n = (b - 7728) * 256 + t;
    if (n < N_NODES) atomicAdd(&hist[graph_id[n]], 1);
    __syncthreads();
    if (t < BSZ) { int v = hist[t]; if (v) atomicAdd(&gcount[t], v); }
  }
}

// ---------------- 2-phase exclusive scan over NBIN2 bins ----------
__global__ __launch_bounds__(256) void k_scanA(const int* __restrict__ cnt,
                                               int* __restrict__ bsum) {
  __shared__ int red[256];
  const int t = threadIdx.x;
  int4 v = *(const int4*)(cnt + blockIdx.x * 1024 + t * 4);
  red[t] = v.x + v.y + v.z + v.w;
  __syncthreads();
  for (int off = 128; off > 0; off >>= 1) {
    if (t < off) red[t] += red[t + off];
    __syncthreads();
  }
  if (t == 0) bsum[blockIdx.x] = red[0];
}

__global__ __launch_bounds__(256) void k_scanC(const int* __restrict__ cnt,
                                               const int* __restrict__ bsum,
                                               int* __restrict__ row_ptr2,
                                               int* __restrict__ cursor) {
  __shared__ int ts[256], bsx[256];
  const int t = threadIdx.x;
  const int base = blockIdx.x * 1024 + t * 4;
  int4 v = *(const int4*)(cnt + base);
  const int s = v.x + v.y + v.z + v.w;
  ts[t]  = s;
  bsx[t] = bsum[t];
  __syncthreads();
  for (int off = 1; off < 256; off <<= 1) {   // inclusive Hillis-Steele, both arrays
    int a = (t >= off) ? ts[t - off]  : 0;
    int c = (t >= off) ? bsx[t - off] : 0;
    __syncthreads();
    ts[t] += a; bsx[t] += c;
    __syncthreads();
  }
  const int boff = (blockIdx.x == 0) ? 0 : bsx[blockIdx.x - 1];
  int ex = ts[t] - s + boff;
  int4 w = { ex, ex + v.x, ex + v.x + v.y, ex + v.x + v.y + v.z };
  *(int4*)(row_ptr2 + base) = w;
  *(int4*)(cursor + base) = w;
}

// ---------------- fill: edge_off[p] = src, grouped by (dst,rel) ----
__global__ void k_fill(const int* __restrict__ src, const int* __restrict__ dst,
                       const int* __restrict__ etype, int* __restrict__ cursor,
                       int* __restrict__ edge_off) {
  int e = blockIdx.x * blockDim.x + threadIdx.x;
  if (e < NEDGE) {
    int p = atomicAdd(&cursor[dst[e] * 8 + etype[e]], 1);
    edge_off[p] = src[e];
  }
}

// ---------------- fused layer: aggregate (dst,rel) bins -> LDS A -> K=1152 GEMM ------
// h_next[n,o] = relu( sum_r sum_i agg[n,r,i] Wrel[r,i,o] + sum_i h[n,i] Wself[i,o] )
// A_sh[node][r*128+i] = sum over bin edges of h[src]; A_sh[node][1024+i] = h[n,i].
__global__ __launch_bounds__(256, 2) void k_layer(
    const unsigned short* __restrict__ Hin,   // [N,128] bf16
    const unsigned short* __restrict__ Bt2,   // [128 o][1152 kk] bf16 (this layer)
    const int* __restrict__ row_ptr2,         // [N*8+1] bin offsets
    const int* __restrict__ edge_off,         // [E] src node ids
    unsigned short* __restrict__ Hout)        // [N,128] bf16
{
  __shared__ unsigned short A_sh[32 * ASTR];  // 74.2 KB
  const int tid  = threadIdx.x;
  const int wv   = tid >> 6, lane = tid & 63;
  const int half = lane >> 5, li = lane & 31;
  const int l15  = lane & 15, quad = lane >> 4;
  const int n0   = blockIdx.x * 32;
  const unsigned int* Hu = (const unsigned int*)Hin;

  // ---- phase A: per wave 8 nodes; per half-wave 4 concurrent bin streams ----
  for (int batch = 0; batch < 8; ++batch) {
    const int nl = batch * 4 + wv;
    const int n  = n0 + nl;
    const int rb = n * 8 + half * 4;
    int eb[4], ee[4];
    eb[0] = row_ptr2[rb + 0];
    eb[1] = row_ptr2[rb + 1];
    eb[2] = row_ptr2[rb + 2];
    eb[3] = row_ptr2[rb + 3];
    ee[0] = eb[1]; ee[1] = eb[2]; ee[2] = eb[3];
    ee[3] = row_ptr2[rb + 4];
    int steps = max(max(ee[0] - eb[0], ee[1] - eb[1]),
                    max(ee[2] - eb[2], ee[3] - eb[3]));
    float acc[4][4] = {};
    for (int it = 0; it < steps; ++it) {
      #pragma unroll
      for (int s = 0; s < 4; ++s) {
        const int e = eb[s] + it;
        const bool ok = e < ee[s];
        const int idx = ok ? e : 0;
        const int srcn = edge_off[idx];
        uint2 u = *(const uint2*)(Hu + (size_t)srcn * 64 + li * 2);
        const unsigned int ux = ok ? u.x : 0u;
        const unsigned int uy = ok ? u.y : 0u;
        acc[s][0] += bf2f((unsigned short)(ux & 0xffff));
        acc[s][1] += bf2f((unsigned short)(ux >> 16));
        acc[s][2] += bf2f((unsigned short)(uy & 0xffff));
        acc[s][3] += bf2f((unsigned short)(uy >> 16));
      }
    }
    #pragma unroll
    for (int s = 0; s < 4; ++s) {
      ushort4 w4 = { f2bf(acc[s][0]), f2bf(acc[s][1]), f2bf(acc[s][2]), f2bf(acc[s][3]) };
      *(ushort4*)(A_sh + nl * ASTR + (half * 4 + s) * H + li * 4) = w4;
    }
    // self chunk: copy bf16 row verbatim (2 cols per lane)
    *(unsigned int*)(A_sh + nl * ASTR + 1024 + lane * 2) = Hu[(size_t)n * 64 + lane];
  }
  __syncthreads();

  // ---- phase B: C[32][128] = A_sh(32x1152) @ Bt2^T; wave wv owns out cols wv*32.. ----
  float4v c00 = {0.f,0.f,0.f,0.f}, c01 = {0.f,0.f,0.f,0.f};
  float4v c10 = {0.f,0.f,0.f,0.f}, c11 = {0.f,0.f,0.f,0.f};
  const unsigned short* Bw = Bt2 + (size_t)(wv * 32) * NKK;
  #pragma unroll 4
  for (int ks = 0; ks < 36; ++ks) {
    const int kk = ks * 32 + quad * 8;
    short8 a0 = *(const short8*)(A_sh + l15 * ASTR + kk);
    short8 a1 = *(const short8*)(A_sh + (16 + l15) * ASTR + kk);
    short8 b0 = *(const short8*)(Bw + (size_t)l15 * NKK + kk);
    short8 b1 = *(const short8*)(Bw + (size_t)(16 + l15) * NKK + kk);
    c00 = __builtin_amdgcn_mfma_f32_16x16x32_bf16(a0, b0, c00, 0, 0, 0);
    c01 = __builtin_amdgcn_mfma_f32_16x16x32_bf16(a0, b1, c01, 0, 0, 0);
    c10 = __builtin_amdgcn_mfma_f32_16x16x32_bf16(a1, b0, c10, 0, 0, 0);
    c11 = __builtin_amdgcn_mfma_f32_16x16x32_bf16(a1, b1, c11, 0, 0, 0);
  }
  __syncthreads();

  // ---- epilogue: relu -> bf16 via LDS repack -> coalesced uint4 stores ----
  #pragma unroll
  for (int r = 0; r < 4; ++r) {
    const int row0 = quad * 4 + r, row1 = 16 + quad * 4 + r;
    const int col0 = wv * 32 + l15, col1 = wv * 32 + 16 + l15;
    A_sh[row0 * 136 + col0] = f2bf(fmaxf(c00[r], 0.f));
    A_sh[row0 * 136 + col1] = f2bf(fmaxf(c01[r], 0.f));
    A_sh[row1 * 136 + col0] = f2bf(fmaxf(c10[r], 0.f));
    A_sh[row1 * 136 + col1] = f2bf(fmaxf(c11[r], 0.f));
  }
  __syncthreads();
  #pragma unroll
  for (int rep = 0; rep < 2; ++rep) {
    const int ch = rep * 256 + tid;       // 512 uint4 chunks = 32 rows x 16
    const int node = ch >> 4, c = ch & 15;
    *(uint4*)(Hout + (size_t)(n0 + node) * H + c * 8) =
        *(const uint4*)(A_sh + node * 136 + c * 8);
  }
}

// ---------------- per-graph partial mean from bf16 h (8-way split + float atomics) ----
__global__ void k_gmean(const unsigned short* __restrict__ hb, float* __restrict__ gmean)
{
  const int g = blockIdx.x, l = blockIdx.y, c = blockIdx.z, t = threadIdx.x;  // 64
  const unsigned short* base =
      hb + ((size_t)(l + 1) * N_NODES + (size_t)g * NPG + (size_t)c * (NPG / 8)) * H + t * 2;
  float sx = 0.f, sy = 0.f;
  for (int i = 0; i < 125; ++i) {
    unsigned int u = *(const unsigned int*)(base + (size_t)i * H);
    sx += bf2f((unsigned short)(u & 0xffff));
    sy += bf2f((unsigned short)(u >> 16));
  }
  float* gp = gmean + (size_t)g * (NL * H) + l * H + t * 2;
  atomicAdd(gp, sx);
  atomicAdd(gp + 1, sy);
}

// ---------------- readout ----------------
__global__ __launch_bounds__(128) void k_final(
    const unsigned short* __restrict__ hb, const float* __restrict__ gmean,
    const int* __restrict__ gcount,
    const float* __restrict__ rel_tb, const float* __restrict__ Zn,
    const float* __restrict__ projW, const float* __restrict__ projB,
    const float* __restrict__ fcW, const float* __restrict__ fcB,
    const float* __restrict__ repSeq,
    const int* __restrict__ head_ids, const int* __restrict__ tail_ids,
    const int* __restrict__ rel_lab, float* __restrict__ out)
{
  const int b = blockIdx.x;
  const int o = threadIdx.x;   // 128
  __shared__ float gm[384], hf[384], tf[384];
  __shared__ float go[128], ho[128], t_o[128], re[128], rs[128], sv[128];
  __shared__ float lg[128], pr[128], red[128], att[3];

  const int hid = head_ids[b], tlid = tail_ids[b], rl = rel_lab[b];
  const float cinv = 1.f / (float)gcount[b];
  #pragma unroll
  for (int l = 0; l < NL; ++l) {
    gm[l * H + o] = gmean[(size_t)b * (NL * H) + l * H + o] * cinv;
    hf[l * H + o] = bf2f(hb[((size_t)(l + 1) * N_NODES + hid) * H + o]);
    tf[l * H + o] = bf2f(hb[((size_t)(l + 1) * N_NODES + tlid) * H + o]);
  }
  re[o] = rel_tb[rl * H + o];
  rs[o] = repSeq[b * H + o];
  __syncthreads();

  float pb = projB[o];
  float sg = pb, sh = pb, st = pb;
  for (int i = 0; i < NL * H; ++i) {
    float wv = projW[i * H + o];
    sg = fmaf(gm[i], wv, sg);
    sh = fmaf(hf[i], wv, sh);
    st = fmaf(tf[i], wv, st);
  }
  go[o] = (sg > 0.f) ? sg : 0.01f * sg;
  ho[o] = sh;
  t_o[o] = st;
  __syncthreads();

  {
    const int k = o & 63;
    const float* v = (o < 64) ? ho : t_o;
    float s = 0.f;
    for (int i = 0; i < H; ++i) s = fmaf(v[i], Zn[k * H + i], s);
    lg[o] = s;
  }
  __syncthreads();
  if (o < 2) {
    float* l0 = &lg[o * 64];
    float* p0 = &pr[o * 64];
    float mx = l0[0];
    for (int k = 1; k < 64; ++k) mx = fmaxf(mx, l0[k]);
    float sum = 0.f;
    for (int k = 0; k < 64; ++k) { float e = __expf(l0[k] - mx); p0[k] = e; sum += e; }
    float inv = 1.f / sum;
    for (int k = 0; k < 64; ++k) p0[k] *= inv;
  }
  __syncthreads();
  {
    float s1 = 0.f, s2 = 0.f;
    for (int k = 0; k < 64; ++k) {
      float z = Zn[k * H + o];
      s1 = fmaf(pr[k], z, s1);
      s2 = fmaf(pr[64 + k], z, s2);
    }
    s1 = 1.f / (1.f + __expf(-s1));
    s2 = 1.f / (1.f + __expf(-s2));
    sv[o] = s1 * s2;
  }
  __syncthreads();
  if (o == 0) {
    float d0 = 0.f, d1 = 0.f, d2 = 0.f;
    for (int i = 0; i < H; ++i) { d0 += re[i] * go[i]; d1 += re[i] * rs[i]; d2 += re[i] * sv[i]; }
    float mx = fmaxf(d0, fmaxf(d1, d2));
    float e0 = __expf(d0 - mx), e1 = __expf(d1 - mx), e2 = __expf(d2 - mx);
    float inv = 1.f / (e0 + e1 + e2);
    att[0] = e0 * inv; att[1] = e1 * inv; att[2] = e2 * inv;
  }
  __syncthreads();
  float va = att[0] * go[o] + att[1] * rs[o] + att[2] * sv[o];

  float p = 0.f;
  p = fmaf(hf[o],       fcW[o],       p);
  p = fmaf(hf[128 + o], fcW[128 + o], p);
  p = fmaf(hf[256 + o], fcW[256 + o], p);
  p = fmaf(tf[o],       fcW[384 + o], p);
  p = fmaf(tf[128 + o], fcW[512 + o], p);
  p = fmaf(tf[256 + o], fcW[640 + o], p);
  p = fmaf(re[o],       fcW[768 + o], p);
  p = fmaf(va,          fcW[896 + o], p);
  red[o] = p;
  __syncthreads();
  if (o == 0) {
    float s = 0.f;
    for (int i = 0; i < 128; ++i) s += red[i];
    out[b] = s + fcB[0];
  }
}

extern "C" void kernel_launch(void* const* d_in, const int* in_sizes, int n_in,
                              void* d_out, int out_size, void* d_ws, size_t ws_size,
                              hipStream_t stream) {
  const float* x        = (const float*)d_in[0];
  const float* W_rel    = (const float*)d_in[1];
  const float* W_self   = (const float*)d_in[2];
  const float* rel_tb   = (const float*)d_in[3];
  const float* Zn       = (const float*)d_in[4];
  const float* proj_W   = (const float*)d_in[5];
  const float* proj_b   = (const float*)d_in[6];
  const float* fc_W     = (const float*)d_in[7];
  const float* fc_b     = (const float*)d_in[8];
  const float* rep_seq  = (const float*)d_in[9];
  const int* src      = (const int*)d_in[10];
  const int* dst      = (const int*)d_in[11];
  const int* etype    = (const int*)d_in[12];
  const int* graph_id = (const int*)d_in[13];
  const int* head_ids = (const int*)d_in[14];
  const int* tail_ids = (const int*)d_in[15];
  const int* rel_lab  = (const int*)d_in[16];
  float* out = (float*)d_out;

  // workspace carve (~41 MB), all 16B aligned
  char* w = (char*)d_ws;
  unsigned short* hb  = (unsigned short*)w; w += (size_t)(NL + 1) * N_NODES * H * 2;   // 32.8 MB
  unsigned short* Bt2 = (unsigned short*)w; w += (size_t)NL * H * NKK * 2;             // 0.88 MB
  int* row_ptr2 = (int*)w;  w += (size_t)(NBIN2 + 8) * 4;                              // 1.05 MB
  int* cursor   = (int*)w;  w += (size_t)NBIN2 * 4;                                    // 1.05 MB
  int* edge_off = (int*)w;  w += (size_t)NEDGE * 4;                                    // 2.05 MB
  int* bsum     = (int*)w;  w += (size_t)256 * 4;
  // zero region: cnt | gcount | gmean
  char* z = w;
  int* cnt     = (int*)w;   w += (size_t)NBIN2 * 4;                                    // 1.05 MB
  int* gcount  = (int*)w;   w += (size_t)32 * 4;
  float* gmean = (float*)w; w += (size_t)BSZ * NL * H * 4;
  size_t zbytes = (size_t)(w - z);

  hipMemsetAsync(z, 0, zbytes, stream);
  k_prep <<<7853, 256, 0, stream>>>(x, W_rel, W_self, dst, etype, graph_id, hb, Bt2, cnt, gcount);
  k_scanA<<<NBIN2 / 1024, 256, 0, stream>>>(cnt, bsum);
  k_scanC<<<NBIN2 / 1024, 256, 0, stream>>>(cnt, bsum, row_ptr2, cursor);
  k_fill <<<NEDGE / 256, 256, 0, stream>>>(src, dst, etype, cursor, edge_off);

  for (int l = 0; l < NL; ++l) {
    const unsigned short* hp = hb + (size_t)l * N_NODES * H;
    unsigned short* hn = hb + (size_t)(l + 1) * N_NODES * H;
    k_layer<<<N_NODES / 32, 256, 0, stream>>>(hp, Bt2 + (size_t)l * H * NKK,
                                              row_ptr2, edge_off, hn);
  }
  k_gmean<<<dim3(BSZ, NL, 8), 64, 0, stream>>>(hb, gmean);
  k_final<<<BSZ, H, 0, stream>>>(hb, gmean, gcount, rel_tb, Zn, proj_W, proj_b, fc_W, fc_b,
                                 rep_seq, head_ids, tail_ids, rel_lab, out);
  (void)in_sizes; (void)n_in; (void)out_size; (void)ws_size;
}

// Round 4
// 356.428 us; speedup vs baseline: 1.3425x; 1.3425x over previous
//
#include <hip/hip_runtime.h>

#define N_NODES 32000
#define NPG     1000
#define BSZ     32
#define NEDGE   512000
#define H       128
#define NL      3
#define NR      8
#define NKK     1152    // K dim: 8*128 rel chunks + 128 self chunk
#define NBIN2   262144  // 32768 dst bins x 8 rel sub-bins (pow2-padded; bins >= 256000 empty)

typedef __attribute__((ext_vector_type(8))) short short8;
typedef __attribute__((ext_vector_type(4))) float float4v;

__device__ __forceinline__ float bf2f(unsigned short u) {
  union { unsigned int i; float f; } v;
  v.i = ((unsigned int)u) << 16;
  return v.f;
}
__device__ __forceinline__ unsigned short f2bf(float f) {
  union { float f; unsigned int i; } v;
  v.f = f;
  unsigned int x = v.i;
  return (unsigned short)((x + 0x7FFFu + ((x >> 16) & 1u)) >> 16);  // RNE
}

// direct global->LDS DMA, 16B per lane (dest = wave-uniform base + lane*16)
__device__ __forceinline__ void gl_lds16(const void* g, void* l) {
  __builtin_amdgcn_global_load_lds((__attribute__((address_space(1))) void*)g,
                                   (__attribute__((address_space(3))) void*)l,
                                   16, 0, 0);
}

// ---------------- fused prep: cvtX | cvtB | per-(dst,rel) count | graph hist ----------
__global__ __launch_bounds__(256) void k_prep(
    const float* __restrict__ x, const float* __restrict__ W_rel,
    const float* __restrict__ W_self, const int* __restrict__ dst,
    const int* __restrict__ etype, const int* __restrict__ graph_id,
    unsigned short* __restrict__ hb, unsigned short* __restrict__ Bt,
    int* __restrict__ cnt, int* __restrict__ gcount)
{
  const int b = blockIdx.x, t = threadIdx.x;
  if (b < 4000) {                       // x fp32 -> h0 bf16
    const size_t i = ((size_t)b * 256 + t) * 4;
    float4 v = *(const float4*)(x + i);
    ushort4 u = { f2bf(v.x), f2bf(v.y), f2bf(v.z), f2bf(v.w) };
    *(ushort4*)(hb + i) = u;
  } else if (b < 5728) {                // weights -> Bt2[l][o=0..127][kk=0..1151]
    const int g = (b - 4000) * 256 + t;  // 0..442367 enumerates (l, o, kk)
    const int l = g / (H * NKK);
    const int rem = g - l * (H * NKK);
    const int o = rem / NKK;
    const int kk = rem - o * NKK;
    float v = (kk < 1024)
        ? W_rel[(((size_t)l * NR + (kk >> 7)) * H + (kk & 127)) * H + o]
        : W_self[((size_t)l * H + (kk - 1024)) * H + o];
    Bt[g] = f2bf(v);
  } else if (b < 7728) {                // per-(dst,rel) edge counts
    const int e = (b - 5728) * 256 + t;
    atomicAdd(&cnt[dst[e] * 8 + etype[e]], 1);
  } else {                              // graph histogram (125 blocks)
    __shared__ int hist[BSZ];
    if (t < BSZ) hist[t] = 0;
    __syncthreads();
    const int n = (b - 7728) * 256 + t;
    if (n < N_NODES) atomicAdd(&hist[graph_id[n]], 1);
    __syncthreads();
    if (t < BSZ) { int v = hist[t]; if (v) atomicAdd(&gcount[t], v); }
  }
}

// ---------------- 2-phase exclusive scan over NBIN2 bins ----------
__global__ __launch_bounds__(256) void k_scanA(const int* __restrict__ cnt,
                                               int* __restrict__ bsum) {
  __shared__ int red[256];
  const int t = threadIdx.x;
  int4 v = *(const int4*)(cnt + blockIdx.x * 1024 + t * 4);
  red[t] = v.x + v.y + v.z + v.w;
  __syncthreads();
  for (int off = 128; off > 0; off >>= 1) {
    if (t < off) red[t] += red[t + off];
    __syncthreads();
  }
  if (t == 0) bsum[blockIdx.x] = red[0];
}

__global__ __launch_bounds__(256) void k_scanC(const int* __restrict__ cnt,
                                               const int* __restrict__ bsum,
                                               int* __restrict__ row_ptr2,
                                               int* __restrict__ cursor) {
  __shared__ int ts[256], bsx[256];
  const int t = threadIdx.x;
  const int base = blockIdx.x * 1024 + t * 4;
  int4 v = *(const int4*)(cnt + base);
  const int s = v.x + v.y + v.z + v.w;
  ts[t]  = s;
  bsx[t] = bsum[t];
  __syncthreads();
  for (int off = 1; off < 256; off <<= 1) {   // inclusive Hillis-Steele, both arrays
    int a = (t >= off) ? ts[t - off]  : 0;
    int c = (t >= off) ? bsx[t - off] : 0;
    __syncthreads();
    ts[t] += a; bsx[t] += c;
    __syncthreads();
  }
  const int boff = (blockIdx.x == 0) ? 0 : bsx[blockIdx.x - 1];
  int ex = ts[t] - s + boff;
  int4 w = { ex, ex + v.x, ex + v.x + v.y, ex + v.x + v.y + v.z };
  *(int4*)(row_ptr2 + base) = w;
  *(int4*)(cursor + base) = w;
}

// ---------------- fill: edge_off[p] = src, grouped by (dst,rel) ----
__global__ void k_fill(const int* __restrict__ src, const int* __restrict__ dst,
                       const int* __restrict__ etype, int* __restrict__ cursor,
                       int* __restrict__ edge_off) {
  int e = blockIdx.x * blockDim.x + threadIdx.x;
  if (e < NEDGE) {
    int p = atomicAdd(&cursor[dst[e] * 8 + etype[e]], 1);
    edge_off[p] = src[e];
  }
}

// ---------------- aggregate: A[n][r*128+i] = sum_{e in bin(n,r)} h[src_e][i] ---------
// A[n][1024+i] = h[n][i]. One half-wave per (node, bin-pair {j, j+4}); 2 nodes/block.
// Massive TLP: 128k half-waves, no LDS, tiny VGPR.
__global__ __launch_bounds__(256) void k_agg(
    const unsigned short* __restrict__ Hin,   // [N,128] bf16 (L2/LLC-resident)
    const int* __restrict__ row_ptr2,         // [N*8+1] bin offsets
    const int* __restrict__ edge_off,         // [E] src node ids
    unsigned short* __restrict__ A)           // [N,1152] bf16
{
  const int tid = threadIdx.x;
  const int hw = tid >> 5, li = tid & 31;
  const int nl = hw >> 2, j = hw & 3;
  const int n = blockIdx.x * 2 + nl;
  const unsigned int* Hu = (const unsigned int*)Hin;
  const int rb = n * 8;
  const int b0 = row_ptr2[rb + j],     e0 = row_ptr2[rb + j + 1];
  const int b1 = row_ptr2[rb + j + 4], e1 = row_ptr2[rb + j + 5];
  float a0[4] = {0.f, 0.f, 0.f, 0.f}, a1[4] = {0.f, 0.f, 0.f, 0.f};
  const int steps = max(e0 - b0, e1 - b1);
  for (int it = 0; it < steps; ++it) {
    const int p0 = b0 + it, p1 = b1 + it;
    const bool k0 = p0 < e0, k1 = p1 < e1;
    const int s0 = edge_off[k0 ? p0 : 0];
    const int s1 = edge_off[k1 ? p1 : 0];
    uint2 u0 = *(const uint2*)(Hu + (size_t)s0 * 64 + li * 2);
    uint2 u1 = *(const uint2*)(Hu + (size_t)s1 * 64 + li * 2);
    const unsigned int x0 = k0 ? u0.x : 0u, y0 = k0 ? u0.y : 0u;
    const unsigned int x1 = k1 ? u1.x : 0u, y1 = k1 ? u1.y : 0u;
    a0[0] += bf2f((unsigned short)(x0 & 0xffff));
    a0[1] += bf2f((unsigned short)(x0 >> 16));
    a0[2] += bf2f((unsigned short)(y0 & 0xffff));
    a0[3] += bf2f((unsigned short)(y0 >> 16));
    a1[0] += bf2f((unsigned short)(x1 & 0xffff));
    a1[1] += bf2f((unsigned short)(x1 >> 16));
    a1[2] += bf2f((unsigned short)(y1 & 0xffff));
    a1[3] += bf2f((unsigned short)(y1 >> 16));
  }
  ushort4 w0 = { f2bf(a0[0]), f2bf(a0[1]), f2bf(a0[2]), f2bf(a0[3]) };
  ushort4 w1 = { f2bf(a1[0]), f2bf(a1[1]), f2bf(a1[2]), f2bf(a1[3]) };
  *(ushort4*)(A + (size_t)n * NKK + j * H + li * 4) = w0;
  *(ushort4*)(A + (size_t)n * NKK + (j + 4) * H + li * 4) = w1;
  if (j == 0) {   // self chunk: verbatim copy of h[n]
    uint2 u = *(const uint2*)(Hu + (size_t)n * 64 + li * 2);
    *(uint2*)(A + (size_t)n * NKK + 1024 + li * 4) = u;
  }
}

// ---------------- GEMM: Hout = relu(A[32000x1152] @ Bt2^T[1152x128]) ------------------
// BM=64, BN=128(full), BK=64, dbuf global_load_lds w16, both-sides XOR chunk swizzle.
// 500 blocks x 512 thr; 48KB LDS -> 2 blocks/CU.
__global__ __launch_bounds__(512, 2) void k_gemmA(
    const unsigned short* __restrict__ Ag,    // [32000][1152] bf16
    const unsigned short* __restrict__ Bg,    // [128][1152]   bf16
    unsigned short* __restrict__ Hout)        // [32000][128]  bf16
{
  __shared__ __align__(16) unsigned short pool[24576];  // a0|b0|a1|b1 = 4096|8192|4096|8192
  const int tid = threadIdx.x;
  const int w = tid >> 6, lane = tid & 63;
  const int l15 = lane & 15, quad = lane >> 4;
  const int m0 = blockIdx.x * 64;
  const int rbase = (w & 1) * 32;     // C row group (M)
  const int cbase = (w >> 1) * 32;    // C col group (N)

  float4v acc[2][2];
  #pragma unroll
  for (int i = 0; i < 2; ++i)
    #pragma unroll
    for (int jj = 0; jj < 2; ++jj) acc[i][jj] = (float4v){0.f, 0.f, 0.f, 0.f};

  // prologue: stage tile kt=0 into buf0
  {
    int g = tid, row = g >> 3, c = g & 7;
    gl_lds16(Ag + (size_t)(m0 + row) * NKK + ((c ^ (row & 7)) * 8), pool + (size_t)g * 8);
    gl_lds16(Bg + (size_t)row * NKK + ((c ^ (row & 7)) * 8), pool + 4096 + (size_t)g * 8);
    int g2 = tid + 512, row2 = g2 >> 3, c2 = g2 & 7;
    gl_lds16(Bg + (size_t)row2 * NKK + ((c2 ^ (row2 & 7)) * 8), pool + 4096 + (size_t)g2 * 8);
  }
  __syncthreads();

  #pragma unroll 2
  for (int kt = 0; kt < 18; ++kt) {
    const int cur = kt & 1;
    const unsigned short* ac = cur ? pool + 12288 : pool;
    const unsigned short* bc = cur ? pool + 16384 : pool + 4096;
    if (kt < 17) {   // prefetch next K-tile into the other buffer (m97 pattern)
      unsigned short* an = cur ? pool : pool + 12288;
      unsigned short* bn = cur ? pool + 4096 : pool + 16384;
      const int kb = (kt + 1) * 64;
      int g = tid, row = g >> 3, c = g & 7;
      gl_lds16(Ag + (size_t)(m0 + row) * NKK + kb + ((c ^ (row & 7)) * 8), an + (size_t)g * 8);
      gl_lds16(Bg + (size_t)row * NKK + kb + ((c ^ (row & 7)) * 8), bn + (size_t)g * 8);
      int g2 = tid + 512, row2 = g2 >> 3, c2 = g2 & 7;
      gl_lds16(Bg + (size_t)row2 * NKK + kb + ((c2 ^ (row2 & 7)) * 8), bn + (size_t)g2 * 8);
    }
    #pragma unroll
    for (int s = 0; s < 2; ++s) {
      short8 af[2], bfv[2];
      #pragma unroll
      for (int rf = 0; rf < 2; ++rf) {
        const int row = rbase + rf * 16 + l15;
        af[rf] = *(const short8*)(ac + row * 64 + (((s * 4 + quad) ^ (row & 7)) * 8));
      }
      #pragma unroll
      for (int cf = 0; cf < 2; ++cf) {
        const int o = cbase + cf * 16 + l15;
        bfv[cf] = *(const short8*)(bc + o * 64 + (((s * 4 + quad) ^ (o & 7)) * 8));
      }
      #pragma unroll
      for (int rf = 0; rf < 2; ++rf)
        #pragma unroll
        for (int cf = 0; cf < 2; ++cf)
          acc[rf][cf] = __builtin_amdgcn_mfma_f32_16x16x32_bf16(af[rf], bfv[cf], acc[rf][cf], 0, 0, 0);
    }
    __syncthreads();
  }

  // epilogue: relu -> bf16 repack in LDS (stride 136) -> coalesced uint4 stores
  #pragma unroll
  for (int rf = 0; rf < 2; ++rf)
    #pragma unroll
    for (int cf = 0; cf < 2; ++cf)
      #pragma unroll
      for (int r = 0; r < 4; ++r) {
        const int row = rbase + rf * 16 + quad * 4 + r;
        const int col = cbase + cf * 16 + l15;
        pool[row * 136 + col] = f2bf(fmaxf(acc[rf][cf][r], 0.f));
      }
  __syncthreads();
  #pragma unroll
  for (int rep = 0; rep < 2; ++rep) {
    const int g = rep * 512 + tid;  // 1024 chunks = 64 rows x 16 (was the R3 bug: only 512 stored)
    const int row = g >> 4, c = g & 15;
    *(uint4*)(Hout + (size_t)(m0 + row) * H + c * 8) = *(const uint4*)(pool + row * 136 + c * 8);
  }
}

// ---------------- per-graph partial mean from bf16 h (8-way split + float atomics) ----
__global__ void k_gmean(const unsigned short* __restrict__ hb, float* __restrict__ gmean)
{
  const int g = blockIdx.x, l = blockIdx.y, c = blockIdx.z, t = threadIdx.x;  // 64
  const unsigned short* base =
      hb + ((size_t)(l + 1) * N_NODES + (size_t)g * NPG + (size_t)c * (NPG / 8)) * H + t * 2;
  float sx = 0.f, sy = 0.f;
  for (int i = 0; i < 125; ++i) {
    unsigned int u = *(const unsigned int*)(base + (size_t)i * H);
    sx += bf2f((unsigned short)(u & 0xffff));
    sy += bf2f((unsigned short)(u >> 16));
  }
  float* gp = gmean + (size_t)g * (NL * H) + l * H + t * 2;
  atomicAdd(gp, sx);
  atomicAdd(gp + 1, sy);
}

// ---------------- readout ----------------
__global__ __launch_bounds__(128) void k_final(
    const unsigned short* __restrict__ hb, const float* __restrict__ gmean,
    const int* __restrict__ gcount,
    const float* __restrict__ rel_tb, const float* __restrict__ Zn,
    const float* __restrict__ projW, const float* __restrict__ projB,
    const float* __restrict__ fcW, const float* __restrict__ fcB,
    const float* __restrict__ repSeq,
    const int* __restrict__ head_ids, const int* __restrict__ tail_ids,
    const int* __restrict__ rel_lab, float* __restrict__ out)
{
  const int b = blockIdx.x;
  const int o = threadIdx.x;   // 128
  __shared__ float gm[384], hf[384], tf[384];
  __shared__ float go[128], ho[128], t_o[128], re[128], rs[128], sv[128];
  __shared__ float lg[128], pr[128], red[128], att[3];

  const int hid = head_ids[b], tlid = tail_ids[b], rl = rel_lab[b];
  const float cinv = 1.f / (float)gcount[b];
  #pragma unroll
  for (int l = 0; l < NL; ++l) {
    gm[l * H + o] = gmean[(size_t)b * (NL * H) + l * H + o] * cinv;
    hf[l * H + o] = bf2f(hb[((size_t)(l + 1) * N_NODES + hid) * H + o]);
    tf[l * H + o] = bf2f(hb[((size_t)(l + 1) * N_NODES + tlid) * H + o]);
  }
  re[o] = rel_tb[rl * H + o];
  rs[o] = repSeq[b * H + o];
  __syncthreads();

  float pb = projB[o];
  float sg = pb, sh = pb, st = pb;
  for (int i = 0; i < NL * H; ++i) {
    float wv = projW[i * H + o];
    sg = fmaf(gm[i], wv, sg);
    sh = fmaf(hf[i], wv, sh);
    st = fmaf(tf[i], wv, st);
  }
  go[o] = (sg > 0.f) ? sg : 0.01f * sg;
  ho[o] = sh;
  t_o[o] = st;
  __syncthreads();

  {
    const int k = o & 63;
    const float* v = (o < 64) ? ho : t_o;
    float s = 0.f;
    for (int i = 0; i < H; ++i) s = fmaf(v[i], Zn[k * H + i], s);
    lg[o] = s;
  }
  __syncthreads();
  if (o < 2) {
    float* l0 = &lg[o * 64];
    float* p0 = &pr[o * 64];
    float mx = l0[0];
    for (int k = 1; k < 64; ++k) mx = fmaxf(mx, l0[k]);
    float sum = 0.f;
    for (int k = 0; k < 64; ++k) { float e = __expf(l0[k] - mx); p0[k] = e; sum += e; }
    float inv = 1.f / sum;
    for (int k = 0; k < 64; ++k) p0[k] *= inv;
  }
  __syncthreads();
  {
    float s1 = 0.f, s2 = 0.f;
    for (int k = 0; k < 64; ++k) {
      float z = Zn[k * H + o];
      s1 = fmaf(pr[k], z, s1);
      s2 = fmaf(pr[64 + k], z, s2);
    }
    s1 = 1.f / (1.f + __expf(-s1));
    s2 = 1.f / (1.f + __expf(-s2));
    sv[o] = s1 * s2;
  }
  __syncthreads();
  if (o == 0) {
    float d0 = 0.f, d1 = 0.f, d2 = 0.f;
    for (int i = 0; i < H; ++i) { d0 += re[i] * go[i]; d1 += re[i] * rs[i]; d2 += re[i] * sv[i]; }
    float mx = fmaxf(d0, fmaxf(d1, d2));
    float e0 = __expf(d0 - mx), e1 = __expf(d1 - mx), e2 = __expf(d2 - mx);
    float inv = 1.f / (e0 + e1 + e2);
    att[0] = e0 * inv; att[1] = e1 * inv; att[2] = e2 * inv;
  }
  __syncthreads();
  float va = att[0] * go[o] + att[1] * rs[o] + att[2] * sv[o];

  float p = 0.f;
  p = fmaf(hf[o],       fcW[o],       p);
  p = fmaf(hf[128 + o], fcW[128 + o], p);
  p = fmaf(hf[256 + o], fcW[256 + o], p);
  p = fmaf(tf[o],       fcW[384 + o], p);
  p = fmaf(tf[128 + o], fcW[512 + o], p);
  p = fmaf(tf[256 + o], fcW[640 + o], p);
  p = fmaf(re[o],       fcW[768 + o], p);
  p = fmaf(va,          fcW[896 + o], p);
  red[o] = p;
  __syncthreads();
  if (o == 0) {
    float s = 0.f;
    for (int i = 0; i < 128; ++i) s += red[i];
    out[b] = s + fcB[0];
  }
}

extern "C" void kernel_launch(void* const* d_in, const int* in_sizes, int n_in,
                              void* d_out, int out_size, void* d_ws, size_t ws_size,
                              hipStream_t stream) {
  const float* x        = (const float*)d_in[0];
  const float* W_rel    = (const float*)d_in[1];
  const float* W_self   = (const float*)d_in[2];
  const float* rel_tb   = (const float*)d_in[3];
  const float* Zn       = (const float*)d_in[4];
  const float* proj_W   = (const float*)d_in[5];
  const float* proj_b   = (const float*)d_in[6];
  const float* fc_W     = (const float*)d_in[7];
  const float* fc_b     = (const float*)d_in[8];
  const float* rep_seq  = (const float*)d_in[9];
  const int* src      = (const int*)d_in[10];
  const int* dst      = (const int*)d_in[11];
  const int* etype    = (const int*)d_in[12];
  const int* graph_id = (const int*)d_in[13];
  const int* head_ids = (const int*)d_in[14];
  const int* tail_ids = (const int*)d_in[15];
  const int* rel_lab  = (const int*)d_in[16];
  float* out = (float*)d_out;

  // workspace carve (~115 MB), all 16B aligned
  char* w = (char*)d_ws;
  unsigned short* A   = (unsigned short*)w; w += (size_t)N_NODES * NKK * 2;            // 73.7 MB
  unsigned short* hb  = (unsigned short*)w; w += (size_t)(NL + 1) * N_NODES * H * 2;   // 32.8 MB
  unsigned short* Bt2 = (unsigned short*)w; w += (size_t)NL * H * NKK * 2;             // 0.88 MB
  int* row_ptr2 = (int*)w;  w += (size_t)(NBIN2 + 8) * 4;                              // 1.05 MB
  int* cursor   = (int*)w;  w += (size_t)NBIN2 * 4;                                    // 1.05 MB
  int* edge_off = (int*)w;  w += (size_t)NEDGE * 4;                                    // 2.05 MB
  int* bsum     = (int*)w;  w += (size_t)256 * 4;
  // zero region: cnt | gcount | gmean
  char* z = w;
  int* cnt     = (int*)w;   w += (size_t)NBIN2 * 4;                                    // 1.05 MB
  int* gcount  = (int*)w;   w += (size_t)32 * 4;
  float* gmean = (float*)w; w += (size_t)BSZ * NL * H * 4;
  size_t zbytes = (size_t)(w - z);

  hipMemsetAsync(z, 0, zbytes, stream);
  k_prep <<<7853, 256, 0, stream>>>(x, W_rel, W_self, dst, etype, graph_id, hb, Bt2, cnt, gcount);
  k_scanA<<<NBIN2 / 1024, 256, 0, stream>>>(cnt, bsum);
  k_scanC<<<NBIN2 / 1024, 256, 0, stream>>>(cnt, bsum, row_ptr2, cursor);
  k_fill <<<NEDGE / 256, 256, 0, stream>>>(src, dst, etype, cursor, edge_off);

  for (int l = 0; l < NL; ++l) {
    const unsigned short* hp = hb + (size_t)l * N_NODES * H;
    unsigned short* hn = hb + (size_t)(l + 1) * N_NODES * H;
    k_agg  <<<N_NODES / 2, 256, 0, stream>>>(hp, row_ptr2, edge_off, A);
    k_gemmA<<<N_NODES / 64, 512, 0, stream>>>(A, Bt2 + (size_t)l * H * NKK, hn);
  }
  k_gmean<<<dim3(BSZ, NL, 8), 64, 0, stream>>>(hb, gmean);
  k_final<<<BSZ, H, 0, stream>>>(hb, gmean, gcount, rel_tb, Zn, proj_W, proj_b, fc_W, fc_b,
                                 rep_seq, head_ids, tail_ids, rel_lab, out);
  (void)in_sizes; (void)n_in; (void)out_size; (void)ws_size;
}

// Round 5
// 343.424 us; speedup vs baseline: 1.3934x; 1.0379x over previous
//
#include <hip/hip_runtime.h>

#define N_NODES 32000
#define NPG     1000
#define BSZ     32
#define NEDGE   512000
#define H       128
#define NL      3
#define NR      8
#define NKK     1152    // K dim: 8*128 rel chunks + 128 self chunk
#define NBIN2   262144  // 32768 dst bins x 8 rel sub-bins (pow2-padded; bins >= 256000 empty)

typedef __attribute__((ext_vector_type(8))) short short8;
typedef __attribute__((ext_vector_type(4))) float float4v;

__device__ __forceinline__ float bf2f(unsigned short u) {
  union { unsigned int i; float f; } v;
  v.i = ((unsigned int)u) << 16;
  return v.f;
}
__device__ __forceinline__ unsigned short f2bf(float f) {
  union { float f; unsigned int i; } v;
  v.f = f;
  unsigned int x = v.i;
  return (unsigned short)((x + 0x7FFFu + ((x >> 16) & 1u)) >> 16);  // RNE
}

// direct global->LDS DMA, 16B per lane (dest = wave-uniform base + lane*16)
__device__ __forceinline__ void gl_lds16(const void* g, void* l) {
  __builtin_amdgcn_global_load_lds((__attribute__((address_space(1))) void*)g,
                                   (__attribute__((address_space(3))) void*)l,
                                   16, 0, 0);
}

// ---------------- fused prep: cvtX | cvtB | per-(dst,rel) count | graph hist ----------
__global__ __launch_bounds__(256) void k_prep(
    const float* __restrict__ x, const float* __restrict__ W_rel,
    const float* __restrict__ W_self, const int* __restrict__ dst,
    const int* __restrict__ etype, const int* __restrict__ graph_id,
    unsigned short* __restrict__ hb, unsigned short* __restrict__ Bt,
    int* __restrict__ cnt, int* __restrict__ gcount)
{
  const int b = blockIdx.x, t = threadIdx.x;
  if (b < 4000) {                       // x fp32 -> h0 bf16
    const size_t i = ((size_t)b * 256 + t) * 4;
    float4 v = *(const float4*)(x + i);
    ushort4 u = { f2bf(v.x), f2bf(v.y), f2bf(v.z), f2bf(v.w) };
    *(ushort4*)(hb + i) = u;
  } else if (b < 5728) {                // weights -> Bt2[l][o=0..127][kk=0..1151]
    const int g = (b - 4000) * 256 + t;  // 0..442367 enumerates (l, o, kk)
    const int l = g / (H * NKK);
    const int rem = g - l * (H * NKK);
    const int o = rem / NKK;
    const int kk = rem - o * NKK;
    float v = (kk < 1024)
        ? W_rel[(((size_t)l * NR + (kk >> 7)) * H + (kk & 127)) * H + o]
        : W_self[((size_t)l * H + (kk - 1024)) * H + o];
    Bt[g] = f2bf(v);
  } else if (b < 7728) {                // per-(dst,rel) edge counts
    const int e = (b - 5728) * 256 + t;
    atomicAdd(&cnt[dst[e] * 8 + etype[e]], 1);
  } else {                              // graph histogram (125 blocks)
    __shared__ int hist[BSZ];
    if (t < BSZ) hist[t] = 0;
    __syncthreads();
    const int n = (b - 7728) * 256 + t;
    if (n < N_NODES) atomicAdd(&hist[graph_id[n]], 1);
    __syncthreads();
    if (t < BSZ) { int v = hist[t]; if (v) atomicAdd(&gcount[t], v); }
  }
}

// ---------------- 2-phase exclusive scan over NBIN2 bins ----------
__global__ __launch_bounds__(256) void k_scanA(const int* __restrict__ cnt,
                                               int* __restrict__ bsum) {
  __shared__ int red[256];
  const int t = threadIdx.x;
  int4 v = *(const int4*)(cnt + blockIdx.x * 1024 + t * 4);
  red[t] = v.x + v.y + v.z + v.w;
  __syncthreads();
  for (int off = 128; off > 0; off >>= 1) {
    if (t < off) red[t] += red[t + off];
    __syncthreads();
  }
  if (t == 0) bsum[blockIdx.x] = red[0];
}

__global__ __launch_bounds__(256) void k_scanC(const int* __restrict__ cnt,
                                               const int* __restrict__ bsum,
                                               int* __restrict__ row_ptr2,
                                               int* __restrict__ cursor) {
  __shared__ int ts[256], bsx[256];
  const int t = threadIdx.x;
  const int base = blockIdx.x * 1024 + t * 4;
  int4 v = *(const int4*)(cnt + base);
  const int s = v.x + v.y + v.z + v.w;
  ts[t]  = s;
  bsx[t] = bsum[t];
  __syncthreads();
  for (int off = 1; off < 256; off <<= 1) {   // inclusive Hillis-Steele, both arrays
    int a = (t >= off) ? ts[t - off]  : 0;
    int c = (t >= off) ? bsx[t - off] : 0;
    __syncthreads();
    ts[t] += a; bsx[t] += c;
    __syncthreads();
  }
  const int boff = (blockIdx.x == 0) ? 0 : bsx[blockIdx.x - 1];
  int ex = ts[t] - s + boff;
  int4 w = { ex, ex + v.x, ex + v.x + v.y, ex + v.x + v.y + v.z };
  *(int4*)(row_ptr2 + base) = w;
  *(int4*)(cursor + base) = w;
}

// ---------------- fill: edge_off[p] = src, grouped by (dst,rel) ----
__global__ void k_fill(const int* __restrict__ src, const int* __restrict__ dst,
                       const int* __restrict__ etype, int* __restrict__ cursor,
                       int* __restrict__ edge_off) {
  int e = blockIdx.x * blockDim.x + threadIdx.x;
  if (e < NEDGE) {
    int p = atomicAdd(&cursor[dst[e] * 8 + etype[e]], 1);
    edge_off[p] = src[e];
  }
}

// ---------------- aggregate: A[n][r*128+i] = sum_{e in bin(n,r)} h[src_e][i] ---------
// v2: one half-wave per (node, rel) bin; 4-wide masked load batch (idx loads issued
// together, 4 row loads in flight). A[n][1024+i] = h[n][i]. 32000 blocks x 256 thr.
__global__ __launch_bounds__(256) void k_agg(
    const unsigned short* __restrict__ Hin,   // [N,128] bf16 (L2/LLC-resident)
    const int* __restrict__ row_ptr2,         // [N*8+1] bin offsets
    const int* __restrict__ edge_off,         // [E] src node ids
    unsigned short* __restrict__ A)           // [N,1152] bf16
{
  const int tid = threadIdx.x;
  const int j = tid >> 5;           // rel bin 0..7
  const int li = tid & 31;          // covers cols li*4 .. li*4+3
  const int n = blockIdx.x;
  const unsigned int* Hu = (const unsigned int*)Hin;
  const int b = row_ptr2[n * 8 + j];
  const int e = row_ptr2[n * 8 + j + 1];
  float a0 = 0.f, a1 = 0.f, a2 = 0.f, a3 = 0.f;
#define ACCW(xx, yy) { \
    a0 += bf2f((unsigned short)((xx) & 0xffff)); \
    a1 += bf2f((unsigned short)((xx) >> 16));    \
    a2 += bf2f((unsigned short)((yy) & 0xffff)); \
    a3 += bf2f((unsigned short)((yy) >> 16)); }
  for (int k = b; k < e; k += 4) {
    const bool v1 = (k + 1) < e, v2 = (k + 2) < e, v3 = (k + 3) < e;
    const int o0 = edge_off[k];
    const int o1 = edge_off[v1 ? k + 1 : k];
    const int o2 = edge_off[v2 ? k + 2 : k];
    const int o3 = edge_off[v3 ? k + 3 : k];
    uint2 u0 = *(const uint2*)(Hu + (size_t)o0 * 64 + li * 2);
    uint2 u1 = *(const uint2*)(Hu + (size_t)o1 * 64 + li * 2);
    uint2 u2 = *(const uint2*)(Hu + (size_t)o2 * 64 + li * 2);
    uint2 u3 = *(const uint2*)(Hu + (size_t)o3 * 64 + li * 2);
    ACCW(u0.x, u0.y)
    ACCW(v1 ? u1.x : 0u, v1 ? u1.y : 0u)   // bf16 0x0000 == +0.0f
    ACCW(v2 ? u2.x : 0u, v2 ? u2.y : 0u)
    ACCW(v3 ? u3.x : 0u, v3 ? u3.y : 0u)
  }
#undef ACCW
  ushort4 w4 = { f2bf(a0), f2bf(a1), f2bf(a2), f2bf(a3) };
  *(ushort4*)(A + (size_t)n * NKK + j * H + li * 4) = w4;
  if (j == 0) {   // self chunk: verbatim copy of h[n]
    uint2 u = *(const uint2*)(Hu + (size_t)n * 64 + li * 2);
    *(uint2*)(A + (size_t)n * NKK + 1024 + li * 4) = u;
  }
}

// ---------------- GEMM: Hout = relu(A[32000x1152] @ Bt2^T[1152x128]) ------------------
// v3: 256 thr / 4 waves; per-wave 32x64 out (2x4 frags) -> 16 MFMA + 12 ds_read per
// barrier (m97 ratio). BM=64, BN=128, BK=64, dbuf gl_lds w16, both-sides XOR swizzle.
// LDS 48KB -> 3 blocks/CU; grid 500.
__global__ __launch_bounds__(256, 3) void k_gemmA(
    const unsigned short* __restrict__ Ag,    // [32000][1152] bf16
    const unsigned short* __restrict__ Bg,    // [128][1152]   bf16
    unsigned short* __restrict__ Hout)        // [32000][128]  bf16
{
  __shared__ __align__(16) unsigned short pool[24576];  // a0[4096] b0[8192] a1[4096] b1[8192]
  const int tid = threadIdx.x;
  const int w = tid >> 6, lane = tid & 63;
  const int l15 = lane & 15, quad = lane >> 4;
  const int m0 = blockIdx.x * 64;
  const int rbase = (w & 1) * 32;     // C row group (M): 0 or 32
  const int cbase = (w >> 1) * 64;    // C col group (N): 0 or 64

  float4v acc[2][4];
  #pragma unroll
  for (int i = 0; i < 2; ++i)
    #pragma unroll
    for (int jj = 0; jj < 4; ++jj) acc[i][jj] = (float4v){0.f, 0.f, 0.f, 0.f};

  // prologue: stage K-tile 0 into buf0
  {
    #pragma unroll
    for (int rep = 0; rep < 2; ++rep) {
      const int g = rep * 256 + tid, row = g >> 3, c = g & 7;
      gl_lds16(Ag + (size_t)(m0 + row) * NKK + ((c ^ (row & 7)) * 8), pool + (size_t)g * 8);
    }
    #pragma unroll
    for (int rep = 0; rep < 4; ++rep) {
      const int g = rep * 256 + tid, row = g >> 3, c = g & 7;
      gl_lds16(Bg + (size_t)row * NKK + ((c ^ (row & 7)) * 8), pool + 4096 + (size_t)g * 8);
    }
  }
  __syncthreads();

  #pragma unroll 2
  for (int kt = 0; kt < 18; ++kt) {
    const int cur = kt & 1;
    const unsigned short* ac = pool + (cur ? 12288 : 0);
    const unsigned short* bc = pool + (cur ? 16384 : 4096);
    if (kt < 17) {   // prefetch next K-tile into the other buffer
      unsigned short* an = pool + (cur ? 0 : 12288);
      unsigned short* bn = pool + (cur ? 4096 : 16384);
      const int kb = (kt + 1) * 64;
      #pragma unroll
      for (int rep = 0; rep < 2; ++rep) {
        const int g = rep * 256 + tid, row = g >> 3, c = g & 7;
        gl_lds16(Ag + (size_t)(m0 + row) * NKK + kb + ((c ^ (row & 7)) * 8), an + (size_t)g * 8);
      }
      #pragma unroll
      for (int rep = 0; rep < 4; ++rep) {
        const int g = rep * 256 + tid, row = g >> 3, c = g & 7;
        gl_lds16(Bg + (size_t)row * NKK + kb + ((c ^ (row & 7)) * 8), bn + (size_t)g * 8);
      }
    }
    #pragma unroll
    for (int s = 0; s < 2; ++s) {
      const int c = s * 4 + quad;    // 16B chunk index within 128B row
      short8 af[2], bfv[4];
      #pragma unroll
      for (int i = 0; i < 2; ++i) {
        const int row = rbase + i * 16 + l15;
        af[i] = *(const short8*)(ac + row * 64 + ((c ^ (row & 7)) * 8));
      }
      #pragma unroll
      for (int jj = 0; jj < 4; ++jj) {
        const int orow = cbase + jj * 16 + l15;
        bfv[jj] = *(const short8*)(bc + orow * 64 + ((c ^ (orow & 7)) * 8));
      }
      #pragma unroll
      for (int i = 0; i < 2; ++i)
        #pragma unroll
        for (int jj = 0; jj < 4; ++jj)
          acc[i][jj] = __builtin_amdgcn_mfma_f32_16x16x32_bf16(af[i], bfv[jj], acc[i][jj], 0, 0, 0);
    }
    __syncthreads();
  }

  // epilogue: relu -> bf16 repack in LDS (stride 136) -> coalesced uint4 stores
  #pragma unroll
  for (int i = 0; i < 2; ++i)
    #pragma unroll
    for (int jj = 0; jj < 4; ++jj)
      #pragma unroll
      for (int r = 0; r < 4; ++r) {
        const int row = rbase + i * 16 + quad * 4 + r;
        const int col = cbase + jj * 16 + l15;
        pool[row * 136 + col] = f2bf(fmaxf(acc[i][jj][r], 0.f));
      }
  __syncthreads();
  #pragma unroll
  for (int rep = 0; rep < 4; ++rep) {
    const int g = rep * 256 + tid;  // 1024 chunks = 64 rows x 16
    const int row = g >> 4, c = g & 15;
    *(uint4*)(Hout + (size_t)(m0 + row) * H + c * 8) = *(const uint4*)(pool + row * 136 + c * 8);
  }
}

// ---------------- per-graph partial mean from bf16 h (8-way split + float atomics) ----
__global__ void k_gmean(const unsigned short* __restrict__ hb, float* __restrict__ gmean)
{
  const int g = blockIdx.x, l = blockIdx.y, c = blockIdx.z, t = threadIdx.x;  // 64
  const unsigned short* base =
      hb + ((size_t)(l + 1) * N_NODES + (size_t)g * NPG + (size_t)c * (NPG / 8)) * H + t * 2;
  float sx = 0.f, sy = 0.f;
  for (int i = 0; i < 125; ++i) {
    unsigned int u = *(const unsigned int*)(base + (size_t)i * H);
    sx += bf2f((unsigned short)(u & 0xffff));
    sy += bf2f((unsigned short)(u >> 16));
  }
  float* gp = gmean + (size_t)g * (NL * H) + l * H + t * 2;
  atomicAdd(gp, sx);
  atomicAdd(gp + 1, sy);
}

// ---------------- readout ----------------
__global__ __launch_bounds__(128) void k_final(
    const unsigned short* __restrict__ hb, const float* __restrict__ gmean,
    const int* __restrict__ gcount,
    const float* __restrict__ rel_tb, const float* __restrict__ Zn,
    const float* __restrict__ projW, const float* __restrict__ projB,
    const float* __restrict__ fcW, const float* __restrict__ fcB,
    const float* __restrict__ repSeq,
    const int* __restrict__ head_ids, const int* __restrict__ tail_ids,
    const int* __restrict__ rel_lab, float* __restrict__ out)
{
  const int b = blockIdx.x;
  const int o = threadIdx.x;   // 128
  __shared__ float gm[384], hf[384], tf[384];
  __shared__ float go[128], ho[128], t_o[128], re[128], rs[128], sv[128];
  __shared__ float lg[128], pr[128], red[128], att[3];

  const int hid = head_ids[b], tlid = tail_ids[b], rl = rel_lab[b];
  const float cinv = 1.f / (float)gcount[b];
  #pragma unroll
  for (int l = 0; l < NL; ++l) {
    gm[l * H + o] = gmean[(size_t)b * (NL * H) + l * H + o] * cinv;
    hf[l * H + o] = bf2f(hb[((size_t)(l + 1) * N_NODES + hid) * H + o]);
    tf[l * H + o] = bf2f(hb[((size_t)(l + 1) * N_NODES + tlid) * H + o]);
  }
  re[o] = rel_tb[rl * H + o];
  rs[o] = repSeq[b * H + o];
  __syncthreads();

  float pb = projB[o];
  float sg = pb, sh = pb, st = pb;
  for (int i = 0; i < NL * H; ++i) {
    float wv = projW[i * H + o];
    sg = fmaf(gm[i], wv, sg);
    sh = fmaf(hf[i], wv, sh);
    st = fmaf(tf[i], wv, st);
  }
  go[o] = (sg > 0.f) ? sg : 0.01f * sg;
  ho[o] = sh;
  t_o[o] = st;
  __syncthreads();

  {
    const int k = o & 63;
    const float* v = (o < 64) ? ho : t_o;
    float s = 0.f;
    for (int i = 0; i < H; ++i) s = fmaf(v[i], Zn[k * H + i], s);
    lg[o] = s;
  }
  __syncthreads();
  if (o < 2) {
    float* l0 = &lg[o * 64];
    float* p0 = &pr[o * 64];
    float mx = l0[0];
    for (int k = 1; k < 64; ++k) mx = fmaxf(mx, l0[k]);
    float sum = 0.f;
    for (int k = 0; k < 64; ++k) { float e = __expf(l0[k] - mx); p0[k] = e; sum += e; }
    float inv = 1.f / sum;
    for (int k = 0; k < 64; ++k) p0[k] *= inv;
  }
  __syncthreads();
  {
    float s1 = 0.f, s2 = 0.f;
    for (int k = 0; k < 64; ++k) {
      float z = Zn[k * H + o];
      s1 = fmaf(pr[k], z, s1);
      s2 = fmaf(pr[64 + k], z, s2);
    }
    s1 = 1.f / (1.f + __expf(-s1));
    s2 = 1.f / (1.f + __expf(-s2));
    sv[o] = s1 * s2;
  }
  __syncthreads();
  if (o == 0) {
    float d0 = 0.f, d1 = 0.f, d2 = 0.f;
    for (int i = 0; i < H; ++i) { d0 += re[i] * go[i]; d1 += re[i] * rs[i]; d2 += re[i] * sv[i]; }
    float mx = fmaxf(d0, fmaxf(d1, d2));
    float e0 = __expf(d0 - mx), e1 = __expf(d1 - mx), e2 = __expf(d2 - mx);
    float inv = 1.f / (e0 + e1 + e2);
    att[0] = e0 * inv; att[1] = e1 * inv; att[2] = e2 * inv;
  }
  __syncthreads();
  float va = att[0] * go[o] + att[1] * rs[o] + att[2] * sv[o];

  float p = 0.f;
  p = fmaf(hf[o],       fcW[o],       p);
  p = fmaf(hf[128 + o], fcW[128 + o], p);
  p = fmaf(hf[256 + o], fcW[256 + o], p);
  p = fmaf(tf[o],       fcW[384 + o], p);
  p = fmaf(tf[128 + o], fcW[512 + o], p);
  p = fmaf(tf[256 + o], fcW[640 + o], p);
  p = fmaf(re[o],       fcW[768 + o], p);
  p = fmaf(va,          fcW[896 + o], p);
  red[o] = p;
  __syncthreads();
  if (o == 0) {
    float s = 0.f;
    for (int i = 0; i < 128; ++i) s += red[i];
    out[b] = s + fcB[0];
  }
}

extern "C" void kernel_launch(void* const* d_in, const int* in_sizes, int n_in,
                              void* d_out, int out_size, void* d_ws, size_t ws_size,
                              hipStream_t stream) {
  const float* x        = (const float*)d_in[0];
  const float* W_rel    = (const float*)d_in[1];
  const float* W_self   = (const float*)d_in[2];
  const float* rel_tb   = (const float*)d_in[3];
  const float* Zn       = (const float*)d_in[4];
  const float* proj_W   = (const float*)d_in[5];
  const float* proj_b   = (const float*)d_in[6];
  const float* fc_W     = (const float*)d_in[7];
  const float* fc_b     = (const float*)d_in[8];
  const float* rep_seq  = (const float*)d_in[9];
  const int* src      = (const int*)d_in[10];
  const int* dst      = (const int*)d_in[11];
  const int* etype    = (const int*)d_in[12];
  const int* graph_id = (const int*)d_in[13];
  const int* head_ids = (const int*)d_in[14];
  const int* tail_ids = (const int*)d_in[15];
  const int* rel_lab  = (const int*)d_in[16];
  float* out = (float*)d_out;

  // workspace carve (~115 MB), all 16B aligned
  char* w = (char*)d_ws;
  unsigned short* A   = (unsigned short*)w; w += (size_t)N_NODES * NKK * 2;            // 73.7 MB
  unsigned short* hb  = (unsigned short*)w; w += (size_t)(NL + 1) * N_NODES * H * 2;   // 32.8 MB
  unsigned short* Bt2 = (unsigned short*)w; w += (size_t)NL * H * NKK * 2;             // 0.88 MB
  int* row_ptr2 = (int*)w;  w += (size_t)(NBIN2 + 8) * 4;                              // 1.05 MB
  int* cursor   = (int*)w;  w += (size_t)NBIN2 * 4;                                    // 1.05 MB
  int* edge_off = (int*)w;  w += (size_t)NEDGE * 4;                                    // 2.05 MB
  int* bsum     = (int*)w;  w += (size_t)256 * 4;
  // zero region: cnt | gcount | gmean
  char* z = w;
  int* cnt     = (int*)w;   w += (size_t)NBIN2 * 4;                                    // 1.05 MB
  int* gcount  = (int*)w;   w += (size_t)32 * 4;
  float* gmean = (float*)w; w += (size_t)BSZ * NL * H * 4;
  size_t zbytes = (size_t)(w - z);

  hipMemsetAsync(z, 0, zbytes, stream);
  k_prep <<<7853, 256, 0, stream>>>(x, W_rel, W_self, dst, etype, graph_id, hb, Bt2, cnt, gcount);
  k_scanA<<<NBIN2 / 1024, 256, 0, stream>>>(cnt, bsum);
  k_scanC<<<NBIN2 / 1024, 256, 0, stream>>>(cnt, bsum, row_ptr2, cursor);
  k_fill <<<NEDGE / 256, 256, 0, stream>>>(src, dst, etype, cursor, edge_off);

  for (int l = 0; l < NL; ++l) {
    const unsigned short* hp = hb + (size_t)l * N_NODES * H;
    unsigned short* hn = hb + (size_t)(l + 1) * N_NODES * H;
    k_agg  <<<N_NODES, 256, 0, stream>>>(hp, row_ptr2, edge_off, A);
    k_gemmA<<<N_NODES / 64, 256, 0, stream>>>(A, Bt2 + (size_t)l * H * NKK, hn);
  }
  k_gmean<<<dim3(BSZ, NL, 8), 64, 0, stream>>>(hb, gmean);
  k_final<<<BSZ, H, 0, stream>>>(hb, gmean, gcount, rel_tb, Zn, proj_W, proj_b, fc_W, fc_b,
                                 rep_seq, head_ids, tail_ids, rel_lab, out);
  (void)in_sizes; (void)n_in; (void)out_size; (void)ws_size;
}

// Round 6
// 333.316 us; speedup vs baseline: 1.4356x; 1.0303x over previous
//
#include <hip/hip_runtime.h>

#define N_NODES 32000
#define NPG     1000
#define BSZ     32
#define NEDGE   512000
#define H       128
#define NL      3
#define NR      8
#define NKK     1152    // B K dim: 8*128 rel chunks + 128 self chunk
#define NKA     1024    // A K dim (rel chunks only; self read from h directly)
#define NBIN2   262144  // 32768 dst bins x 8 rel sub-bins (pow2-padded; bins >= 256000 empty)

typedef __attribute__((ext_vector_type(8))) short short8;
typedef __attribute__((ext_vector_type(4))) float float4v;

__device__ __forceinline__ float bf2f(unsigned short u) {
  union { unsigned int i; float f; } v;
  v.i = ((unsigned int)u) << 16;
  return v.f;
}
__device__ __forceinline__ unsigned short f2bf(float f) {
  union { float f; unsigned int i; } v;
  v.f = f;
  unsigned int x = v.i;
  return (unsigned short)((x + 0x7FFFu + ((x >> 16) & 1u)) >> 16);  // RNE
}

// direct global->LDS DMA, 16B per lane (dest = wave-uniform base + lane*16)
__device__ __forceinline__ void gl_lds16(const void* g, void* l) {
  __builtin_amdgcn_global_load_lds((__attribute__((address_space(1))) void*)g,
                                   (__attribute__((address_space(3))) void*)l,
                                   16, 0, 0);
}

// ---------------- fused prep: cvtX | cvtB | per-(dst,rel) count | graph hist ----------
__global__ __launch_bounds__(256) void k_prep(
    const float* __restrict__ x, const float* __restrict__ W_rel,
    const float* __restrict__ W_self, const int* __restrict__ dst,
    const int* __restrict__ etype, const int* __restrict__ graph_id,
    unsigned short* __restrict__ hb, unsigned short* __restrict__ Bt,
    int* __restrict__ cnt, int* __restrict__ gcount)
{
  const int b = blockIdx.x, t = threadIdx.x;
  if (b < 4000) {                       // x fp32 -> h0 bf16
    const size_t i = ((size_t)b * 256 + t) * 4;
    float4 v = *(const float4*)(x + i);
    ushort4 u = { f2bf(v.x), f2bf(v.y), f2bf(v.z), f2bf(v.w) };
    *(ushort4*)(hb + i) = u;
  } else if (b < 5728) {                // weights -> Bt2[l][o=0..127][kk=0..1151]
    const int g = (b - 4000) * 256 + t;  // 0..442367 enumerates (l, o, kk)
    const int l = g / (H * NKK);
    const int rem = g - l * (H * NKK);
    const int o = rem / NKK;
    const int kk = rem - o * NKK;
    float v = (kk < 1024)
        ? W_rel[(((size_t)l * NR + (kk >> 7)) * H + (kk & 127)) * H + o]
        : W_self[((size_t)l * H + (kk - 1024)) * H + o];
    Bt[g] = f2bf(v);
  } else if (b < 7728) {                // per-(dst,rel) edge counts
    const int e = (b - 5728) * 256 + t;
    atomicAdd(&cnt[dst[e] * 8 + etype[e]], 1);
  } else {                              // graph histogram (125 blocks)
    __shared__ int hist[BSZ];
    if (t < BSZ) hist[t] = 0;
    __syncthreads();
    const int n = (b - 7728) * 256 + t;
    if (n < N_NODES) atomicAdd(&hist[graph_id[n]], 1);
    __syncthreads();
    if (t < BSZ) { int v = hist[t]; if (v) atomicAdd(&gcount[t], v); }
  }
}

// ---------------- 2-phase exclusive scan over NBIN2 bins ----------
__global__ __launch_bounds__(256) void k_scanA(const int* __restrict__ cnt,
                                               int* __restrict__ bsum) {
  __shared__ int red[256];
  const int t = threadIdx.x;
  int4 v = *(const int4*)(cnt + blockIdx.x * 1024 + t * 4);
  red[t] = v.x + v.y + v.z + v.w;
  __syncthreads();
  for (int off = 128; off > 0; off >>= 1) {
    if (t < off) red[t] += red[t + off];
    __syncthreads();
  }
  if (t == 0) bsum[blockIdx.x] = red[0];
}

__global__ __launch_bounds__(256) void k_scanC(const int* __restrict__ cnt,
                                               const int* __restrict__ bsum,
                                               int* __restrict__ row_ptr2,
                                               int* __restrict__ cursor) {
  __shared__ int ts[256], bsx[256];
  const int t = threadIdx.x;
  const int base = blockIdx.x * 1024 + t * 4;
  int4 v = *(const int4*)(cnt + base);
  const int s = v.x + v.y + v.z + v.w;
  ts[t]  = s;
  bsx[t] = bsum[t];
  __syncthreads();
  for (int off = 1; off < 256; off <<= 1) {   // inclusive Hillis-Steele, both arrays
    int a = (t >= off) ? ts[t - off]  : 0;
    int c = (t >= off) ? bsx[t - off] : 0;
    __syncthreads();
    ts[t] += a; bsx[t] += c;
    __syncthreads();
  }
  const int boff = (blockIdx.x == 0) ? 0 : bsx[blockIdx.x - 1];
  int ex = ts[t] - s + boff;
  int4 w = { ex, ex + v.x, ex + v.x + v.y, ex + v.x + v.y + v.z };
  *(int4*)(row_ptr2 + base) = w;
  *(int4*)(cursor + base) = w;
}

// ---------------- fill: edge_off[p] = src, grouped by (dst,rel) ----
__global__ void k_fill(const int* __restrict__ src, const int* __restrict__ dst,
                       const int* __restrict__ etype, int* __restrict__ cursor,
                       int* __restrict__ edge_off) {
  int e = blockIdx.x * blockDim.x + threadIdx.x;
  if (e < NEDGE) {
    int p = atomicAdd(&cursor[dst[e] * 8 + etype[e]], 1);
    edge_off[p] = src[e];
  }
}

// ---------------- aggregate: A[n][r*128+i] = sum_{e in bin(n,r)} h[src_e][i] ---------
// v4: half-wave per (node,rel) bin; uint4 row loads (16 lanes/row); lane-parity p
// handles edges k, k+2, ... ; parities combined by shfl_xor(16). 2 slots/parity
// in flight = 4 edges/iteration. No self chunk (GEMM reads h directly).
__global__ __launch_bounds__(256) void k_agg(
    const unsigned short* __restrict__ Hin,   // [N,128] bf16
    const int* __restrict__ row_ptr2,         // [N*8+1] bin offsets
    const int* __restrict__ edge_off,         // [E] src node ids
    unsigned short* __restrict__ A)           // [N,1024] bf16
{
  const int tid = threadIdx.x;
  const int j  = tid >> 5;          // rel bin 0..7
  const int li = tid & 31;
  const int p  = li >> 4;           // edge parity
  const int q  = li & 15;           // col chunk: cols q*8 .. q*8+7
  const int n  = blockIdx.x;
  const uint4* H4 = (const uint4*)Hin;   // one h row = 16 uint4
  const int b = row_ptr2[n * 8 + j];
  const int e = row_ptr2[n * 8 + j + 1];
  float acc[8] = {0.f, 0.f, 0.f, 0.f, 0.f, 0.f, 0.f, 0.f};
#define ACC8(u, ok) { \
    const unsigned int xx = (ok) ? (u).x : 0u, yy = (ok) ? (u).y : 0u; \
    const unsigned int zz = (ok) ? (u).z : 0u, ww = (ok) ? (u).w : 0u; \
    acc[0] += bf2f((unsigned short)(xx & 0xffff)); \
    acc[1] += bf2f((unsigned short)(xx >> 16));    \
    acc[2] += bf2f((unsigned short)(yy & 0xffff)); \
    acc[3] += bf2f((unsigned short)(yy >> 16));    \
    acc[4] += bf2f((unsigned short)(zz & 0xffff)); \
    acc[5] += bf2f((unsigned short)(zz >> 16));    \
    acc[6] += bf2f((unsigned short)(ww & 0xffff)); \
    acc[7] += bf2f((unsigned short)(ww >> 16)); }
  for (int k = b + p; k < e; k += 4) {   // this parity's edges: k, k+2
    const int k1 = k + 2;
    const bool v1 = k1 < e;
    const int o0 = edge_off[k];
    const int o1 = edge_off[v1 ? k1 : k];
    uint4 u0 = H4[(size_t)o0 * 16 + q];
    uint4 u1 = H4[(size_t)o1 * 16 + q];
    ACC8(u0, true)
    ACC8(u1, v1)
  }
#undef ACC8
  #pragma unroll
  for (int i = 0; i < 8; ++i) acc[i] += __shfl_xor(acc[i], 16);
  if (p == 0) {
    uint4 w;
    w.x = (unsigned int)f2bf(acc[0]) | ((unsigned int)f2bf(acc[1]) << 16);
    w.y = (unsigned int)f2bf(acc[2]) | ((unsigned int)f2bf(acc[3]) << 16);
    w.z = (unsigned int)f2bf(acc[4]) | ((unsigned int)f2bf(acc[5]) << 16);
    w.w = (unsigned int)f2bf(acc[6]) | ((unsigned int)f2bf(acc[7]) << 16);
    *(uint4*)(A + (size_t)n * NKA + j * H + q * 8) = w;
  }
}

// ---------------- GEMM: Hout = relu([A | h] @ Bt2^T), K = 1024 + 128 ------------------
// v4: kt 0..15 stage from A (stride 1024); kt 16,17 stage self cols from Hin
// (stride 128). Fused per-graph mean accumulation in epilogue (replaces k_gmean).
// 256 thr / 4 waves; per-wave 32x64 out; dbuf gl_lds w16; both-sides XOR swizzle.
__global__ __launch_bounds__(256, 3) void k_gemmA(
    const unsigned short* __restrict__ Ag,    // [32000][1024] bf16
    const unsigned short* __restrict__ Bg,    // [128][1152]   bf16
    const unsigned short* __restrict__ Hin,   // [32000][128]  bf16 (self operand)
    unsigned short* __restrict__ Hout,        // [32000][128]  bf16
    float* __restrict__ gmean, int layer)
{
  __shared__ __align__(16) unsigned short pool[24576];  // a0[4096] b0[8192] a1[4096] b1[8192]
  const int tid = threadIdx.x;
  const int w = tid >> 6, lane = tid & 63;
  const int l15 = lane & 15, quad = lane >> 4;
  const int m0 = blockIdx.x * 64;
  const int rbase = (w & 1) * 32;     // C row group (M): 0 or 32
  const int cbase = (w >> 1) * 64;    // C col group (N): 0 or 64

  float4v acc[2][4];
  #pragma unroll
  for (int i = 0; i < 2; ++i)
    #pragma unroll
    for (int jj = 0; jj < 4; ++jj) acc[i][jj] = (float4v){0.f, 0.f, 0.f, 0.f};

  // stage helpers: A-side source switches to Hin for the self K-tiles
  auto stageA = [&](unsigned short* dstL, const int kb) {
    #pragma unroll
    for (int rep = 0; rep < 2; ++rep) {
      const int g = rep * 256 + tid, row = g >> 3, c = g & 7;
      const unsigned short* srcp = (kb < NKA)
          ? Ag  + (size_t)(m0 + row) * NKA + kb + ((c ^ (row & 7)) * 8)
          : Hin + (size_t)(m0 + row) * H + (kb - NKA) + ((c ^ (row & 7)) * 8);
      gl_lds16(srcp, dstL + (size_t)g * 8);
    }
  };
  auto stageB = [&](unsigned short* dstL, const int kb) {
    #pragma unroll
    for (int rep = 0; rep < 4; ++rep) {
      const int g = rep * 256 + tid, row = g >> 3, c = g & 7;
      gl_lds16(Bg + (size_t)row * NKK + kb + ((c ^ (row & 7)) * 8), dstL + (size_t)g * 8);
    }
  };

  stageA(pool, 0);
  stageB(pool + 4096, 0);
  __syncthreads();

  #pragma unroll 2
  for (int kt = 0; kt < 18; ++kt) {
    const int cur = kt & 1;
    const unsigned short* ac = pool + (cur ? 12288 : 0);
    const unsigned short* bc = pool + (cur ? 16384 : 4096);
    if (kt < 17) {   // prefetch next K-tile into the other buffer
      const int kb = (kt + 1) * 64;
      stageA(pool + (cur ? 0 : 12288), kb);
      stageB(pool + (cur ? 4096 : 16384), kb);
    }
    #pragma unroll
    for (int s = 0; s < 2; ++s) {
      const int c = s * 4 + quad;    // 16B chunk index within 128B row
      short8 af[2], bfv[4];
      #pragma unroll
      for (int i = 0; i < 2; ++i) {
        const int row = rbase + i * 16 + l15;
        af[i] = *(const short8*)(ac + row * 64 + ((c ^ (row & 7)) * 8));
      }
      #pragma unroll
      for (int jj = 0; jj < 4; ++jj) {
        const int orow = cbase + jj * 16 + l15;
        bfv[jj] = *(const short8*)(bc + orow * 64 + ((c ^ (orow & 7)) * 8));
      }
      #pragma unroll
      for (int i = 0; i < 2; ++i)
        #pragma unroll
        for (int jj = 0; jj < 4; ++jj)
          acc[i][jj] = __builtin_amdgcn_mfma_f32_16x16x32_bf16(af[i], bfv[jj], acc[i][jj], 0, 0, 0);
    }
    __syncthreads();
  }

  // epilogue: relu -> bf16 repack in LDS (stride 136) -> coalesced uint4 stores
  #pragma unroll
  for (int i = 0; i < 2; ++i)
    #pragma unroll
    for (int jj = 0; jj < 4; ++jj)
      #pragma unroll
      for (int r = 0; r < 4; ++r) {
        const int row = rbase + i * 16 + quad * 4 + r;
        const int col = cbase + jj * 16 + l15;
        pool[row * 136 + col] = f2bf(fmaxf(acc[i][jj][r], 0.f));
      }
  __syncthreads();
  #pragma unroll
  for (int rep = 0; rep < 4; ++rep) {
    const int g = rep * 256 + tid;  // 1024 chunks = 64 rows x 16
    const int row = g >> 4, c = g & 15;
    *(uint4*)(Hout + (size_t)(m0 + row) * H + c * 8) = *(const uint4*)(pool + row * 136 + c * 8);
  }

  // fused per-graph mean accumulation (block straddles <= 1 graph boundary)
  const int g0 = m0 / NPG;
  const int bnd = (g0 + 1) * NPG - m0;   // rows of this tile belonging to g0
  if (tid < H) {
    float s0 = 0.f, s1 = 0.f;
    #pragma unroll 8
    for (int r2 = 0; r2 < 64; ++r2) {
      float v = bf2f(pool[r2 * 136 + tid]);
      if (r2 < bnd) s0 += v; else s1 += v;
    }
    atomicAdd(&gmean[(size_t)g0 * (NL * H) + layer * H + tid], s0);
    if (bnd < 64)
      atomicAdd(&gmean[(size_t)(g0 + 1) * (NL * H) + layer * H + tid], s1);
  }
}

// ---------------- readout ----------------
__global__ __launch_bounds__(128) void k_final(
    const unsigned short* __restrict__ hb, const float* __restrict__ gmean,
    const int* __restrict__ gcount,
    const float* __restrict__ rel_tb, const float* __restrict__ Zn,
    const float* __restrict__ projW, const float* __restrict__ projB,
    const float* __restrict__ fcW, const float* __restrict__ fcB,
    const float* __restrict__ repSeq,
    const int* __restrict__ head_ids, const int* __restrict__ tail_ids,
    const int* __restrict__ rel_lab, float* __restrict__ out)
{
  const int b = blockIdx.x;
  const int o = threadIdx.x;   // 128
  __shared__ float gm[384], hf[384], tf[384];
  __shared__ float go[128], ho[128], t_o[128], re[128], rs[128], sv[128];
  __shared__ float lg[128], pr[128], red[128], att[3];

  const int hid = head_ids[b], tlid = tail_ids[b], rl = rel_lab[b];
  const float cinv = 1.f / (float)gcount[b];
  #pragma unroll
  for (int l = 0; l < NL; ++l) {
    gm[l * H + o] = gmean[(size_t)b * (NL * H) + l * H + o] * cinv;
    hf[l * H + o] = bf2f(hb[((size_t)(l + 1) * N_NODES + hid) * H + o]);
    tf[l * H + o] = bf2f(hb[((size_t)(l + 1) * N_NODES + tlid) * H + o]);
  }
  re[o] = rel_tb[rl * H + o];
  rs[o] = repSeq[b * H + o];
  __syncthreads();

  float pb = projB[o];
  float sg = pb, sh = pb, st = pb;
  for (int i = 0; i < NL * H; ++i) {
    float wv = projW[i * H + o];
    sg = fmaf(gm[i], wv, sg);
    sh = fmaf(hf[i], wv, sh);
    st = fmaf(tf[i], wv, st);
  }
  go[o] = (sg > 0.f) ? sg : 0.01f * sg;
  ho[o] = sh;
  t_o[o] = st;
  __syncthreads();

  {
    const int k = o & 63;
    const float* v = (o < 64) ? ho : t_o;
    float s = 0.f;
    for (int i = 0; i < H; ++i) s = fmaf(v[i], Zn[k * H + i], s);
    lg[o] = s;
  }
  __syncthreads();
  if (o < 2) {
    float* l0 = &lg[o * 64];
    float* p0 = &pr[o * 64];
    float mx = l0[0];
    for (int k = 1; k < 64; ++k) mx = fmaxf(mx, l0[k]);
    float sum = 0.f;
    for (int k = 0; k < 64; ++k) { float e = __expf(l0[k] - mx); p0[k] = e; sum += e; }
    float inv = 1.f / sum;
    for (int k = 0; k < 64; ++k) p0[k] *= inv;
  }
  __syncthreads();
  {
    float s1 = 0.f, s2 = 0.f;
    for (int k = 0; k < 64; ++k) {
      float z = Zn[k * H + o];
      s1 = fmaf(pr[k], z, s1);
      s2 = fmaf(pr[64 + k], z, s2);
    }
    s1 = 1.f / (1.f + __expf(-s1));
    s2 = 1.f / (1.f + __expf(-s2));
    sv[o] = s1 * s2;
  }
  __syncthreads();
  if (o == 0) {
    float d0 = 0.f, d1 = 0.f, d2 = 0.f;
    for (int i = 0; i < H; ++i) { d0 += re[i] * go[i]; d1 += re[i] * rs[i]; d2 += re[i] * sv[i]; }
    float mx = fmaxf(d0, fmaxf(d1, d2));
    float e0 = __expf(d0 - mx), e1 = __expf(d1 - mx), e2 = __expf(d2 - mx);
    float inv = 1.f / (e0 + e1 + e2);
    att[0] = e0 * inv; att[1] = e1 * inv; att[2] = e2 * inv;
  }
  __syncthreads();
  float va = att[0] * go[o] + att[1] * rs[o] + att[2] * sv[o];

  float p = 0.f;
  p = fmaf(hf[o],       fcW[o],       p);
  p = fmaf(hf[128 + o], fcW[128 + o], p);
  p = fmaf(hf[256 + o], fcW[256 + o], p);
  p = fmaf(tf[o],       fcW[384 + o], p);
  p = fmaf(tf[128 + o], fcW[512 + o], p);
  p = fmaf(tf[256 + o], fcW[640 + o], p);
  p = fmaf(re[o],       fcW[768 + o], p);
  p = fmaf(va,          fcW[896 + o], p);
  red[o] = p;
  __syncthreads();
  if (o == 0) {
    float s = 0.f;
    for (int i = 0; i < 128; ++i) s += red[i];
    out[b] = s + fcB[0];
  }
}

extern "C" void kernel_launch(void* const* d_in, const int* in_sizes, int n_in,
                              void* d_out, int out_size, void* d_ws, size_t ws_size,
                              hipStream_t stream) {
  const float* x        = (const float*)d_in[0];
  const float* W_rel    = (const float*)d_in[1];
  const float* W_self   = (const float*)d_in[2];
  const float* rel_tb   = (const float*)d_in[3];
  const float* Zn       = (const float*)d_in[4];
  const float* proj_W   = (const float*)d_in[5];
  const float* proj_b   = (const float*)d_in[6];
  const float* fc_W     = (const float*)d_in[7];
  const float* fc_b     = (const float*)d_in[8];
  const float* rep_seq  = (const float*)d_in[9];
  const int* src      = (const int*)d_in[10];
  const int* dst      = (const int*)d_in[11];
  const int* etype    = (const int*)d_in[12];
  const int* graph_id = (const int*)d_in[13];
  const int* head_ids = (const int*)d_in[14];
  const int* tail_ids = (const int*)d_in[15];
  const int* rel_lab  = (const int*)d_in[16];
  float* out = (float*)d_out;

  // workspace carve (~106 MB), all 16B aligned
  char* w = (char*)d_ws;
  unsigned short* A   = (unsigned short*)w; w += (size_t)N_NODES * NKA * 2;            // 65.5 MB
  unsigned short* hb  = (unsigned short*)w; w += (size_t)(NL + 1) * N_NODES * H * 2;   // 32.8 MB
  unsigned short* Bt2 = (unsigned short*)w; w += (size_t)NL * H * NKK * 2;             // 0.88 MB
  int* row_ptr2 = (int*)w;  w += (size_t)(NBIN2 + 8) * 4;                              // 1.05 MB
  int* cursor   = (int*)w;  w += (size_t)NBIN2 * 4;                                    // 1.05 MB
  int* edge_off = (int*)w;  w += (size_t)NEDGE * 4;                                    // 2.05 MB
  int* bsum     = (int*)w;  w += (size_t)256 * 4;
  // zero region: cnt | gcount | gmean
  char* z = w;
  int* cnt     = (int*)w;   w += (size_t)NBIN2 * 4;                                    // 1.05 MB
  int* gcount  = (int*)w;   w += (size_t)32 * 4;
  float* gmean = (float*)w; w += (size_t)BSZ * NL * H * 4;
  size_t zbytes = (size_t)(w - z);

  hipMemsetAsync(z, 0, zbytes, stream);
  k_prep <<<7853, 256, 0, stream>>>(x, W_rel, W_self, dst, etype, graph_id, hb, Bt2, cnt, gcount);
  k_scanA<<<NBIN2 / 1024, 256, 0, stream>>>(cnt, bsum);
  k_scanC<<<NBIN2 / 1024, 256, 0, stream>>>(cnt, bsum, row_ptr2, cursor);
  k_fill <<<NEDGE / 256, 256, 0, stream>>>(src, dst, etype, cursor, edge_off);

  for (int l = 0; l < NL; ++l) {
    const unsigned short* hp = hb + (size_t)l * N_NODES * H;
    unsigned short* hn = hb + (size_t)(l + 1) * N_NODES * H;
    k_agg  <<<N_NODES, 256, 0, stream>>>(hp, row_ptr2, edge_off, A);
    k_gemmA<<<N_NODES / 64, 256, 0, stream>>>(A, Bt2 + (size_t)l * H * NKK, hp, hn, gmean, l);
  }
  k_final<<<BSZ, H, 0, stream>>>(hb, gmean, gcount, rel_tb, Zn, proj_W, proj_b, fc_W, fc_b,
                                 rep_seq, head_ids, tail_ids, rel_lab, out);
  (void)in_sizes; (void)n_in; (void)out_size; (void)ws_size;
}

// Round 7
// 330.208 us; speedup vs baseline: 1.4491x; 1.0094x over previous
//
#include <hip/hip_runtime.h>

#define N_NODES 32000
#define NPG     1000
#define BSZ     32
#define NEDGE   512000
#define H       128
#define NL      3
#define NR      8
#define NKK     1152    // B K dim: 8*128 rel chunks + 128 self chunk
#define NKA     1024    // A K dim (rel chunks only; self read from h directly)
#define NBIN2   262144  // 32768 dst bins x 8 rel sub-bins (pow2-padded; bins >= 256000 empty)

typedef __attribute__((ext_vector_type(8))) short short8;
typedef __attribute__((ext_vector_type(4))) float float4v;

__device__ __forceinline__ float bf2f(unsigned short u) {
  union { unsigned int i; float f; } v;
  v.i = ((unsigned int)u) << 16;
  return v.f;
}
__device__ __forceinline__ unsigned short f2bf(float f) {
  union { float f; unsigned int i; } v;
  v.f = f;
  unsigned int x = v.i;
  return (unsigned short)((x + 0x7FFFu + ((x >> 16) & 1u)) >> 16);  // RNE
}

// direct global->LDS DMA, 16B per lane (dest = wave-uniform base + lane*16)
__device__ __forceinline__ void gl_lds16(const void* g, void* l) {
  __builtin_amdgcn_global_load_lds((__attribute__((address_space(1))) void*)g,
                                   (__attribute__((address_space(3))) void*)l,
                                   16, 0, 0);
}

// ---------------- fused prep: cvtX | cvtB | per-(dst,rel) count | graph hist ----------
__global__ __launch_bounds__(256) void k_prep(
    const float* __restrict__ x, const float* __restrict__ W_rel,
    const float* __restrict__ W_self, const int* __restrict__ dst,
    const int* __restrict__ etype, const int* __restrict__ graph_id,
    unsigned short* __restrict__ hb, unsigned short* __restrict__ Bt,
    int* __restrict__ cnt, int* __restrict__ gcount)
{
  const int b = blockIdx.x, t = threadIdx.x;
  if (b < 4000) {                       // x fp32 -> h0 bf16
    const size_t i = ((size_t)b * 256 + t) * 4;
    float4 v = *(const float4*)(x + i);
    ushort4 u = { f2bf(v.x), f2bf(v.y), f2bf(v.z), f2bf(v.w) };
    *(ushort4*)(hb + i) = u;
  } else if (b < 5728) {                // weights -> Bt2[l][o=0..127][kk=0..1151]
    const int g = (b - 4000) * 256 + t;  // 0..442367 enumerates (l, o, kk)
    const int l = g / (H * NKK);
    const int rem = g - l * (H * NKK);
    const int o = rem / NKK;
    const int kk = rem - o * NKK;
    float v = (kk < 1024)
        ? W_rel[(((size_t)l * NR + (kk >> 7)) * H + (kk & 127)) * H + o]
        : W_self[((size_t)l * H + (kk - 1024)) * H + o];
    Bt[g] = f2bf(v);
  } else if (b < 7728) {                // per-(dst,rel) edge counts
    const int e = (b - 5728) * 256 + t;
    atomicAdd(&cnt[dst[e] * 8 + etype[e]], 1);
  } else {                              // graph histogram (125 blocks)
    __shared__ int hist[BSZ];
    if (t < BSZ) hist[t] = 0;
    __syncthreads();
    const int n = (b - 7728) * 256 + t;
    if (n < N_NODES) atomicAdd(&hist[graph_id[n]], 1);
    __syncthreads();
    if (t < BSZ) { int v = hist[t]; if (v) atomicAdd(&gcount[t], v); }
  }
}

// ---------------- 2-phase exclusive scan over NBIN2 bins ----------
__global__ __launch_bounds__(256) void k_scanA(const int* __restrict__ cnt,
                                               int* __restrict__ bsum) {
  __shared__ int red[256];
  const int t = threadIdx.x;
  int4 v = *(const int4*)(cnt + blockIdx.x * 1024 + t * 4);
  red[t] = v.x + v.y + v.z + v.w;
  __syncthreads();
  for (int off = 128; off > 0; off >>= 1) {
    if (t < off) red[t] += red[t + off];
    __syncthreads();
  }
  if (t == 0) bsum[blockIdx.x] = red[0];
}

__global__ __launch_bounds__(256) void k_scanC(const int* __restrict__ cnt,
                                               const int* __restrict__ bsum,
                                               int* __restrict__ row_ptr2,
                                               int* __restrict__ cursor) {
  __shared__ int ts[256], bsx[256];
  const int t = threadIdx.x;
  const int base = blockIdx.x * 1024 + t * 4;
  int4 v = *(const int4*)(cnt + base);
  const int s = v.x + v.y + v.z + v.w;
  ts[t]  = s;
  bsx[t] = bsum[t];
  __syncthreads();
  for (int off = 1; off < 256; off <<= 1) {   // inclusive Hillis-Steele, both arrays
    int a = (t >= off) ? ts[t - off]  : 0;
    int c = (t >= off) ? bsx[t - off] : 0;
    __syncthreads();
    ts[t] += a; bsx[t] += c;
    __syncthreads();
  }
  const int boff = (blockIdx.x == 0) ? 0 : bsx[blockIdx.x - 1];
  int ex = ts[t] - s + boff;
  int4 w = { ex, ex + v.x, ex + v.x + v.y, ex + v.x + v.y + v.z };
  *(int4*)(row_ptr2 + base) = w;
  *(int4*)(cursor + base) = w;
}

// ---------------- fill: edge_off[p] = src, grouped by (dst,rel) ----
__global__ void k_fill(const int* __restrict__ src, const int* __restrict__ dst,
                       const int* __restrict__ etype, int* __restrict__ cursor,
                       int* __restrict__ edge_off) {
  int e = blockIdx.x * blockDim.x + threadIdx.x;
  if (e < NEDGE) {
    int p = atomicAdd(&cursor[dst[e] * 8 + etype[e]], 1);
    edge_off[p] = src[e];
  }
}

// ---------------- aggregate: A[n][r*128+i] = sum_{e in bin(n,r)} h[src_e][i] ---------
// v4: half-wave per (node,rel) bin; uint4 row loads (16 lanes/row); lane-parity p
// handles edges k, k+2, ... ; parities combined by shfl_xor(16). 2 slots/parity
// in flight = 4 edges/iteration. No self chunk (GEMM reads h directly).
__global__ __launch_bounds__(256) void k_agg(
    const unsigned short* __restrict__ Hin,   // [N,128] bf16
    const int* __restrict__ row_ptr2,         // [N*8+1] bin offsets
    const int* __restrict__ edge_off,         // [E] src node ids
    unsigned short* __restrict__ A)           // [N,1024] bf16
{
  const int tid = threadIdx.x;
  const int j  = tid >> 5;          // rel bin 0..7
  const int li = tid & 31;
  const int p  = li >> 4;           // edge parity
  const int q  = li & 15;           // col chunk: cols q*8 .. q*8+7
  const int n  = blockIdx.x;
  const uint4* H4 = (const uint4*)Hin;   // one h row = 16 uint4
  const int b = row_ptr2[n * 8 + j];
  const int e = row_ptr2[n * 8 + j + 1];
  float acc[8] = {0.f, 0.f, 0.f, 0.f, 0.f, 0.f, 0.f, 0.f};
#define ACC8(u, ok) { \
    const unsigned int xx = (ok) ? (u).x : 0u, yy = (ok) ? (u).y : 0u; \
    const unsigned int zz = (ok) ? (u).z : 0u, ww = (ok) ? (u).w : 0u; \
    acc[0] += bf2f((unsigned short)(xx & 0xffff)); \
    acc[1] += bf2f((unsigned short)(xx >> 16));    \
    acc[2] += bf2f((unsigned short)(yy & 0xffff)); \
    acc[3] += bf2f((unsigned short)(yy >> 16));    \
    acc[4] += bf2f((unsigned short)(zz & 0xffff)); \
    acc[5] += bf2f((unsigned short)(zz >> 16));    \
    acc[6] += bf2f((unsigned short)(ww & 0xffff)); \
    acc[7] += bf2f((unsigned short)(ww >> 16)); }
  for (int k = b + p; k < e; k += 4) {   // this parity's edges: k, k+2
    const int k1 = k + 2;
    const bool v1 = k1 < e;
    const int o0 = edge_off[k];
    const int o1 = edge_off[v1 ? k1 : k];
    uint4 u0 = H4[(size_t)o0 * 16 + q];
    uint4 u1 = H4[(size_t)o1 * 16 + q];
    ACC8(u0, true)
    ACC8(u1, v1)
  }
#undef ACC8
  #pragma unroll
  for (int i = 0; i < 8; ++i) acc[i] += __shfl_xor(acc[i], 16);
  if (p == 0) {
    uint4 w;
    w.x = (unsigned int)f2bf(acc[0]) | ((unsigned int)f2bf(acc[1]) << 16);
    w.y = (unsigned int)f2bf(acc[2]) | ((unsigned int)f2bf(acc[3]) << 16);
    w.z = (unsigned int)f2bf(acc[4]) | ((unsigned int)f2bf(acc[5]) << 16);
    w.w = (unsigned int)f2bf(acc[6]) | ((unsigned int)f2bf(acc[7]) << 16);
    *(uint4*)(A + (size_t)n * NKA + j * H + q * 8) = w;
  }
}

// ---------------- GEMM: Hout = relu([A | h] @ Bt2^T), K = 1024 + 128 ------------------
// v5: counted-vmcnt double-buffer (T4): per K-step wait vmcnt(6) — next tile's 6
// global_load_lds stay in flight under the MFMAs; only the peeled last tile drains.
// kt 0..15 stage from A (stride 1024); kt 16,17 self cols from Hin (stride 128).
// Fused per-graph mean accumulation in epilogue. 256 thr / 4 waves; 32x64 out/wave.
__global__ __launch_bounds__(256, 3) void k_gemmA(
    const unsigned short* __restrict__ Ag,    // [32000][1024] bf16
    const unsigned short* __restrict__ Bg,    // [128][1152]   bf16
    const unsigned short* __restrict__ Hin,   // [32000][128]  bf16 (self operand)
    unsigned short* __restrict__ Hout,        // [32000][128]  bf16
    float* __restrict__ gmean, int layer)
{
  __shared__ __align__(16) unsigned short pool[24576];  // a0[4096] b0[8192] a1[4096] b1[8192]
  const int tid = threadIdx.x;
  const int w = tid >> 6, lane = tid & 63;
  const int l15 = lane & 15, quad = lane >> 4;
  const int m0 = blockIdx.x * 64;
  const int rbase = (w & 1) * 32;     // C row group (M): 0 or 32
  const int cbase = (w >> 1) * 64;    // C col group (N): 0 or 64

  float4v acc[2][4];
  #pragma unroll
  for (int i = 0; i < 2; ++i)
    #pragma unroll
    for (int jj = 0; jj < 4; ++jj) acc[i][jj] = (float4v){0.f, 0.f, 0.f, 0.f};

  // stage helpers: 2 + 4 = 6 gl_lds per thread per K-tile
  auto stageA = [&](unsigned short* dstL, const int kb) {
    #pragma unroll
    for (int rep = 0; rep < 2; ++rep) {
      const int g = rep * 256 + tid, row = g >> 3, c = g & 7;
      const unsigned short* srcp = (kb < NKA)
          ? Ag  + (size_t)(m0 + row) * NKA + kb + ((c ^ (row & 7)) * 8)
          : Hin + (size_t)(m0 + row) * H + (kb - NKA) + ((c ^ (row & 7)) * 8);
      gl_lds16(srcp, dstL + (size_t)g * 8);
    }
  };
  auto stageB = [&](unsigned short* dstL, const int kb) {
    #pragma unroll
    for (int rep = 0; rep < 4; ++rep) {
      const int g = rep * 256 + tid, row = g >> 3, c = g & 7;
      gl_lds16(Bg + (size_t)row * NKK + kb + ((c ^ (row & 7)) * 8), dstL + (size_t)g * 8);
    }
  };
  auto compute = [&](const unsigned short* ac, const unsigned short* bc) {
    #pragma unroll
    for (int s = 0; s < 2; ++s) {
      const int c = s * 4 + quad;    // 16B chunk index within 128B row
      short8 af[2], bfv[4];
      #pragma unroll
      for (int i = 0; i < 2; ++i) {
        const int row = rbase + i * 16 + l15;
        af[i] = *(const short8*)(ac + row * 64 + ((c ^ (row & 7)) * 8));
      }
      #pragma unroll
      for (int jj = 0; jj < 4; ++jj) {
        const int orow = cbase + jj * 16 + l15;
        bfv[jj] = *(const short8*)(bc + orow * 64 + ((c ^ (orow & 7)) * 8));
      }
      #pragma unroll
      for (int i = 0; i < 2; ++i)
        #pragma unroll
        for (int jj = 0; jj < 4; ++jj)
          acc[i][jj] = __builtin_amdgcn_mfma_f32_16x16x32_bf16(af[i], bfv[jj], acc[i][jj], 0, 0, 0);
    }
  };

  // prologue: tile 0 fully staged + drained
  stageA(pool, 0);
  stageB(pool + 4096, 0);
  asm volatile("s_waitcnt vmcnt(0)" ::: "memory");
  __builtin_amdgcn_s_barrier();
  __builtin_amdgcn_sched_barrier(0);

  #pragma unroll 2
  for (int kt = 0; kt < 17; ++kt) {
    const int cur = kt & 1;
    const unsigned short* ac = pool + (cur ? 12288 : 0);
    const unsigned short* bc = pool + (cur ? 16384 : 4096);
    const int kb = (kt + 1) * 64;
    stageA(pool + (cur ? 0 : 12288), kb);       // 6 loads for kt+1, left in flight
    stageB(pool + (cur ? 4096 : 16384), kb);
    asm volatile("s_waitcnt vmcnt(6)" ::: "memory");  // kt's 6 loads complete
    __builtin_amdgcn_s_barrier();
    __builtin_amdgcn_sched_barrier(0);          // pin ds_reads below the wait (rule #18)
    compute(ac, bc);
    __builtin_amdgcn_sched_barrier(0);
    __builtin_amdgcn_s_barrier();               // all reads of buf[cur] done before overwrite
  }
  // peeled last tile (kt = 17): drain its 6 loads
  asm volatile("s_waitcnt vmcnt(0)" ::: "memory");
  __builtin_amdgcn_s_barrier();
  __builtin_amdgcn_sched_barrier(0);
  compute(pool + 12288, pool + 16384);
  __syncthreads();   // all compute done before repack overwrites pool

  // epilogue: relu -> bf16 repack in LDS (stride 136) -> coalesced uint4 stores
  #pragma unroll
  for (int i = 0; i < 2; ++i)
    #pragma unroll
    for (int jj = 0; jj < 4; ++jj)
      #pragma unroll
      for (int r = 0; r < 4; ++r) {
        const int row = rbase + i * 16 + quad * 4 + r;
        const int col = cbase + jj * 16 + l15;
        pool[row * 136 + col] = f2bf(fmaxf(acc[i][jj][r], 0.f));
      }
  __syncthreads();
  #pragma unroll
  for (int rep = 0; rep < 4; ++rep) {
    const int g = rep * 256 + tid;  // 1024 chunks = 64 rows x 16
    const int row = g >> 4, c = g & 15;
    *(uint4*)(Hout + (size_t)(m0 + row) * H + c * 8) = *(const uint4*)(pool + row * 136 + c * 8);
  }

  // fused per-graph mean accumulation (block straddles <= 1 graph boundary)
  const int g0 = m0 / NPG;
  const int bnd = (g0 + 1) * NPG - m0;   // rows of this tile belonging to g0
  if (tid < H) {
    float s0 = 0.f, s1 = 0.f;
    #pragma unroll 8
    for (int r2 = 0; r2 < 64; ++r2) {
      float v = bf2f(pool[r2 * 136 + tid]);
      if (r2 < bnd) s0 += v; else s1 += v;
    }
    atomicAdd(&gmean[(size_t)g0 * (NL * H) + layer * H + tid], s0);
    if (bnd < 64)
      atomicAdd(&gmean[(size_t)(g0 + 1) * (NL * H) + layer * H + tid], s1);
  }
}

// ---------------- readout ----------------
__global__ __launch_bounds__(128) void k_final(
    const unsigned short* __restrict__ hb, const float* __restrict__ gmean,
    const int* __restrict__ gcount,
    const float* __restrict__ rel_tb, const float* __restrict__ Zn,
    const float* __restrict__ projW, const float* __restrict__ projB,
    const float* __restrict__ fcW, const float* __restrict__ fcB,
    const float* __restrict__ repSeq,
    const int* __restrict__ head_ids, const int* __restrict__ tail_ids,
    const int* __restrict__ rel_lab, float* __restrict__ out)
{
  const int b = blockIdx.x;
  const int o = threadIdx.x;   // 128
  __shared__ float gm[384], hf[384], tf[384];
  __shared__ float go[128], ho[128], t_o[128], re[128], rs[128], sv[128];
  __shared__ float lg[128], pr[128], red[128], att[3];

  const int hid = head_ids[b], tlid = tail_ids[b], rl = rel_lab[b];
  const float cinv = 1.f / (float)gcount[b];
  #pragma unroll
  for (int l = 0; l < NL; ++l) {
    gm[l * H + o] = gmean[(size_t)b * (NL * H) + l * H + o] * cinv;
    hf[l * H + o] = bf2f(hb[((size_t)(l + 1) * N_NODES + hid) * H + o]);
    tf[l * H + o] = bf2f(hb[((size_t)(l + 1) * N_NODES + tlid) * H + o]);
  }
  re[o] = rel_tb[rl * H + o];
  rs[o] = repSeq[b * H + o];
  __syncthreads();

  float pb = projB[o];
  float sg = pb, sh = pb, st = pb;
  for (int i = 0; i < NL * H; ++i) {
    float wv = projW[i * H + o];
    sg = fmaf(gm[i], wv, sg);
    sh = fmaf(hf[i], wv, sh);
    st = fmaf(tf[i], wv, st);
  }
  go[o] = (sg > 0.f) ? sg : 0.01f * sg;
  ho[o] = sh;
  t_o[o] = st;
  __syncthreads();

  {
    const int k = o & 63;
    const float* v = (o < 64) ? ho : t_o;
    float s = 0.f;
    for (int i = 0; i < H; ++i) s = fmaf(v[i], Zn[k * H + i], s);
    lg[o] = s;
  }
  __syncthreads();
  if (o < 2) {
    float* l0 = &lg[o * 64];
    float* p0 = &pr[o * 64];
    float mx = l0[0];
    for (int k = 1; k < 64; ++k) mx = fmaxf(mx, l0[k]);
    float sum = 0.f;
    for (int k = 0; k < 64; ++k) { float e = __expf(l0[k] - mx); p0[k] = e; sum += e; }
    float inv = 1.f / sum;
    for (int k = 0; k < 64; ++k) p0[k] *= inv;
  }
  __syncthreads();
  {
    float s1 = 0.f, s2 = 0.f;
    for (int k = 0; k < 64; ++k) {
      float z = Zn[k * H + o];
      s1 = fmaf(pr[k], z, s1);
      s2 = fmaf(pr[64 + k], z, s2);
    }
    s1 = 1.f / (1.f + __expf(-s1));
    s2 = 1.f / (1.f + __expf(-s2));
    sv[o] = s1 * s2;
  }
  __syncthreads();
  if (o == 0) {
    float d0 = 0.f, d1 = 0.f, d2 = 0.f;
    for (int i = 0; i < H; ++i) { d0 += re[i] * go[i]; d1 += re[i] * rs[i]; d2 += re[i] * sv[i]; }
    float mx = fmaxf(d0, fmaxf(d1, d2));
    float e0 = __expf(d0 - mx), e1 = __expf(d1 - mx), e2 = __expf(d2 - mx);
    float inv = 1.f / (e0 + e1 + e2);
    att[0] = e0 * inv; att[1] = e1 * inv; att[2] = e2 * inv;
  }
  __syncthreads();
  float va = att[0] * go[o] + att[1] * rs[o] + att[2] * sv[o];

  float p = 0.f;
  p = fmaf(hf[o],       fcW[o],       p);
  p = fmaf(hf[128 + o], fcW[128 + o], p);
  p = fmaf(hf[256 + o], fcW[256 + o], p);
  p = fmaf(tf[o],       fcW[384 + o], p);
  p = fmaf(tf[128 + o], fcW[512 + o], p);
  p = fmaf(tf[256 + o], fcW[640 + o], p);
  p = fmaf(re[o],       fcW[768 + o], p);
  p = fmaf(va,          fcW[896 + o], p);
  red[o] = p;
  __syncthreads();
  if (o == 0) {
    float s = 0.f;
    for (int i = 0; i < 128; ++i) s += red[i];
    out[b] = s + fcB[0];
  }
}

extern "C" void kernel_launch(void* const* d_in, const int* in_sizes, int n_in,
                              void* d_out, int out_size, void* d_ws, size_t ws_size,
                              hipStream_t stream) {
  const float* x        = (const float*)d_in[0];
  const float* W_rel    = (const float*)d_in[1];
  const float* W_self   = (const float*)d_in[2];
  const float* rel_tb   = (const float*)d_in[3];
  const float* Zn       = (const float*)d_in[4];
  const float* proj_W   = (const float*)d_in[5];
  const float* proj_b   = (const float*)d_in[6];
  const float* fc_W     = (const float*)d_in[7];
  const float* fc_b     = (const float*)d_in[8];
  const float* rep_seq  = (const float*)d_in[9];
  const int* src      = (const int*)d_in[10];
  const int* dst      = (const int*)d_in[11];
  const int* etype    = (const int*)d_in[12];
  const int* graph_id = (const int*)d_in[13];
  const int* head_ids = (const int*)d_in[14];
  const int* tail_ids = (const int*)d_in[15];
  const int* rel_lab  = (const int*)d_in[16];
  float* out = (float*)d_out;

  // workspace carve (~106 MB), all 16B aligned
  char* w = (char*)d_ws;
  unsigned short* A   = (unsigned short*)w; w += (size_t)N_NODES * NKA * 2;            // 65.5 MB
  unsigned short* hb  = (unsigned short*)w; w += (size_t)(NL + 1) * N_NODES * H * 2;   // 32.8 MB
  unsigned short* Bt2 = (unsigned short*)w; w += (size_t)NL * H * NKK * 2;             // 0.88 MB
  int* row_ptr2 = (int*)w;  w += (size_t)(NBIN2 + 8) * 4;                              // 1.05 MB
  int* cursor   = (int*)w;  w += (size_t)NBIN2 * 4;                                    // 1.05 MB
  int* edge_off = (int*)w;  w += (size_t)NEDGE * 4;                                    // 2.05 MB
  int* bsum     = (int*)w;  w += (size_t)256 * 4;
  // zero region: cnt | gcount | gmean
  char* z = w;
  int* cnt     = (int*)w;   w += (size_t)NBIN2 * 4;                                    // 1.05 MB
  int* gcount  = (int*)w;   w += (size_t)32 * 4;
  float* gmean = (float*)w; w += (size_t)BSZ * NL * H * 4;
  size_t zbytes = (size_t)(w - z);

  hipMemsetAsync(z, 0, zbytes, stream);
  k_prep <<<7853, 256, 0, stream>>>(x, W_rel, W_self, dst, etype, graph_id, hb, Bt2, cnt, gcount);
  k_scanA<<<NBIN2 / 1024, 256, 0, stream>>>(cnt, bsum);
  k_scanC<<<NBIN2 / 1024, 256, 0, stream>>>(cnt, bsum, row_ptr2, cursor);
  k_fill <<<NEDGE / 256, 256, 0, stream>>>(src, dst, etype, cursor, edge_off);

  for (int l = 0; l < NL; ++l) {
    const unsigned short* hp = hb + (size_t)l * N_NODES * H;
    unsigned short* hn = hb + (size_t)(l + 1) * N_NODES * H;
    k_agg  <<<N_NODES, 256, 0, stream>>>(hp, row_ptr2, edge_off, A);
    k_gemmA<<<N_NODES / 64, 256, 0, stream>>>(A, Bt2 + (size_t)l * H * NKK, hp, hn, gmean, l);
  }
  k_final<<<BSZ, H, 0, stream>>>(hb, gmean, gcount, rel_tb, Zn, proj_W, proj_b, fc_W, fc_b,
                                 rep_seq, head_ids, tail_ids, rel_lab, out);
  (void)in_sizes; (void)n_in; (void)out_size; (void)ws_size;
}